// Round 15
// baseline (770.705 us; speedup 1.0000x reference)
//
#include <hip/hip_runtime.h>

typedef long long i64;
typedef unsigned short u16;
typedef __attribute__((ext_vector_type(8))) short bf16x8;
typedef __attribute__((ext_vector_type(8))) unsigned short u16x8;
typedef __attribute__((ext_vector_type(4))) unsigned short u16x4;
typedef __attribute__((ext_vector_type(4))) float f32x4;

#define L_  4
#define B_  16
#define T_  512
#define D_  512
#define H_  8
#define DK_ 64
#define DF_ 2048
#define QKSTR 1024         // q|k row stride (u16); v goes straight to vT

#define WLSTRIDE 3407872   // per-layer bf16 weight count (u16)
#define SC2E 0.1803368801111f   // 0.125 * log2(e): score scale, exp2 domain

__device__ __forceinline__ u16 f2b(float f) {            // fp32 -> bf16 RNE
    unsigned u = __float_as_uint(f);
    u += 0x7FFF + ((u >> 16) & 1);
    return (u16)(u >> 16);
}
__device__ __forceinline__ float b2f(u16 b) {
    return __uint_as_float(((unsigned)b) << 16);
}
__device__ __forceinline__ void gld16(const void* g, void* l) {
    __builtin_amdgcn_global_load_lds(
        (const __attribute__((address_space(1))) void*)g,
        (__attribute__((address_space(3))) void*)l, 16, 0, 0);
}

// ---------------------------------------------------------------- fp32->bf16 converts
__global__ __launch_bounds__(256) void cvt1_k(const float* __restrict__ s,
                                              u16* __restrict__ d, int n4)
{
    int id = blockIdx.x * 256 + threadIdx.x;
    if (id >= n4) return;
    float4 u = reinterpret_cast<const float4*>(s)[id];
    u16x4 o; o[0] = f2b(u.x); o[1] = f2b(u.y); o[2] = f2b(u.z); o[3] = f2b(u.w);
    *reinterpret_cast<u16x4*>(d + (i64)id * 4) = o;
}

// all 4 layers' 7 weight tensors -> contiguous bf16 buffers (blockIdx.y = layer)
__global__ __launch_bounds__(256) void cvt7_k(
    const float* __restrict__ wq, const float* __restrict__ wk,
    const float* __restrict__ wv, const float* __restrict__ wp,
    const float* __restrict__ wo, const float* __restrict__ w1,
    const float* __restrict__ w2, u16* __restrict__ dst)
{
    int l = blockIdx.y;
    wq += (i64)l * 262144; wk += (i64)l * 262144; wv += (i64)l * 262144;
    wp += (i64)l * 262144; wo += (i64)l * 262144;
    w1 += (i64)l * 1048576; w2 += (i64)l * 1048576;
    dst += (i64)l * WLSTRIDE;
    int id = blockIdx.x * 256 + threadIdx.x;  // unit = 4 elems; total 851968
    if (id >= 851968) return;
    const float* s; i64 doff;
    if (id < 327680) {
        int seg = id >> 16, off = id & 65535;
        s = seg == 0 ? wq : seg == 1 ? wk : seg == 2 ? wv : seg == 3 ? wp : wo;
        s += (i64)off * 4;
        doff = (i64)seg * 262144 + (i64)off * 4;
    } else {
        int id2 = id - 327680;
        int seg = id2 >> 18, off = id2 & 262143;
        s = (seg ? w2 : w1) + (i64)off * 4;
        doff = 1310720 + (i64)seg * 1048576 + (i64)off * 4;
    }
    float4 u = *reinterpret_cast<const float4*>(s);
    u16x4 o; o[0] = f2b(u.x); o[1] = f2b(u.y); o[2] = f2b(u.z); o[3] = f2b(u.w);
    *reinterpret_cast<u16x4*>(dst + doff) = o;
}

// pack per-layer qkv biases into [L][1536] fp32
__global__ __launch_bounds__(256) void packb_k(const float* __restrict__ bq,
                                               const float* __restrict__ bk,
                                               const float* __restrict__ bv,
                                               float* __restrict__ dst)
{
    int id = blockIdx.x * 256 + threadIdx.x;   // L*1536 = 6144
    if (id >= L_ * 1536) return;
    int l = id / 1536, c = id % 1536;
    float v = (c < 512) ? bq[l * 512 + c]
            : (c < 1024) ? bk[l * 512 + c - 512]
                         : bv[l * 512 + c - 1024];
    dst[id] = v;
}

// ---------------------------------------------------------------- LayerNorm
template<bool OB>
__global__ __launch_bounds__(256) void ln_k(const float* __restrict__ x,
                                            const float* __restrict__ w,
                                            const float* __restrict__ b,
                                            void* __restrict__ outv, int nrows)
{
    int wid  = (blockIdx.x * 256 + threadIdx.x) >> 6;
    int lane = threadIdx.x & 63;
    if (wid >= nrows) return;
    const float* xr = x + (i64)wid * D_;
    float4 u = reinterpret_cast<const float4*>(xr)[lane * 2 + 0];
    float4 v = reinterpret_cast<const float4*>(xr)[lane * 2 + 1];
    float s = u.x + u.y + u.z + u.w + v.x + v.y + v.z + v.w;
    float q = u.x*u.x + u.y*u.y + u.z*u.z + u.w*u.w
            + v.x*v.x + v.y*v.y + v.z*v.z + v.w*v.w;
#pragma unroll
    for (int m = 1; m < 64; m <<= 1) { s += __shfl_xor(s, m); q += __shfl_xor(q, m); }
    float mu   = s * (1.0f / D_);
    float var  = q * (1.0f / D_) - mu * mu;
    float rstd = rsqrtf(var + 1e-5f);
    int c0 = lane * 8;
    float o[8];
    o[0] = (u.x - mu) * rstd * w[c0+0] + b[c0+0];
    o[1] = (u.y - mu) * rstd * w[c0+1] + b[c0+1];
    o[2] = (u.z - mu) * rstd * w[c0+2] + b[c0+2];
    o[3] = (u.w - mu) * rstd * w[c0+3] + b[c0+3];
    o[4] = (v.x - mu) * rstd * w[c0+4] + b[c0+4];
    o[5] = (v.y - mu) * rstd * w[c0+5] + b[c0+5];
    o[6] = (v.z - mu) * rstd * w[c0+6] + b[c0+6];
    o[7] = (v.w - mu) * rstd * w[c0+7] + b[c0+7];
    if (OB) {
        u16x8 ob;
#pragma unroll
        for (int i = 0; i < 8; i++) ob[i] = f2b(o[i]);
        *reinterpret_cast<u16x8*>((u16*)outv + (i64)wid * D_ + c0) = ob;
    } else {
        float4 o0 = {o[0], o[1], o[2], o[3]};
        float4 o1 = {o[4], o[5], o[6], o[7]};
        reinterpret_cast<float4*>((float*)outv + (i64)wid * D_)[lane * 2 + 0] = o0;
        reinterpret_cast<float4*>((float*)outv + (i64)wid * D_)[lane * 2 + 1] = o1;
    }
}

// ---------------------------------------------------------------- rank-1 column bias (bdb only)
__global__ __launch_bounds__(256) void colbias_k(const u16* __restrict__ kb, int ld,
                                                 const float* __restrict__ pbias,
                                                 float* __restrict__ out, int ntok)
{
    int wid  = (blockIdx.x * 256 + threadIdx.x) >> 6;
    int l    = threadIdx.x & 63;
    if (wid >= ntok) return;
    int h = l >> 3, d0 = (l & 7) * 8;
    u16x8 kv = *reinterpret_cast<const u16x8*>(kb + (i64)wid * ld + h * 64 + d0);
    float s = 0.f;
#pragma unroll
    for (int i = 0; i < 8; i++) s += b2f(kv[i]) * pbias[h * 64 + d0 + i];
    s += __shfl_xor(s, 1); s += __shfl_xor(s, 2); s += __shfl_xor(s, 4);
    if ((l & 7) == 0) out[(i64)(wid >> 9) * 4096 + h * 512 + (wid & 511)] = s;
}

// ---------------------------------------------------------------- fused attention
// bds pre-shifted and pre-scaled by SC2E; acb pre-scaled at production.
// exp2-domain softmax, lazy pmax reduce, per-lane deferred l-sum, and
// SOFTWARE-PIPELINED bdr/acf loads (issued one tile ahead, ping-pong regs).
__global__ __launch_bounds__(256, 4) void fattn_k(
    const u16* __restrict__ qkv, const u16* __restrict__ vT_b,
    const float* __restrict__ acb, const u16* __restrict__ bds,
    u16* __restrict__ ctx)
{
    __shared__ u16 kbuf[2][64 * 64];
    __shared__ u16 vbuf[2][64 * 64];
    __shared__ u16 pbuf[64 * 64];

    const int id = blockIdx.x;
    const int h = id & 7, b = (id >> 3) & 15, qt = id >> 7;
    const int i0 = qt * 64;
    const int tid = threadIdx.x;
    const int w = tid >> 6, lane = tid & 63;
    const int lr = lane & 15, g = lane >> 4;
    const int lc = (lane & 7) ^ ((lane >> 3) & 7);

    bf16x8 qw[2];
#pragma unroll
    for (int kk = 0; kk < 2; ++kk)
        qw[kk] = *reinterpret_cast<const bf16x8*>(
            qkv + ((i64)b * T_ + i0 + w * 16 + lr) * QKSTR + h * DK_ + kk * 32 + g * 8);

    {
        const u16* ksrc = qkv + 512 + ((i64)b * T_) * QKSTR + h * DK_;
        const u16* vsrc = vT_b + ((i64)(b * H_ + h) * DK_) * T_;
#pragma unroll
        for (int t2 = 0; t2 < 2; ++t2) {
            int t = w * 2 + t2;
            gld16(ksrc + (i64)(t * 8 + (lane >> 3)) * QKSTR + lc * 8,
                  (char*)&kbuf[0][0] + t * 1024);
            gld16(vsrc + (i64)(t * 8 + (lane >> 3)) * T_ + lc * 8,
                  (char*)&vbuf[0][0] + t * 1024);
        }
    }

    const float* acbh = acb + (i64)b * (H_ * T_) + h * T_;
    const u16* bdsp = bds + (((i64)(b * H_ + h)) << 18)
                          + (i64)(i0 + w * 16 + g * 4) * T_;

    // ping-pong prefetch registers for bd / acb (slot jt&1)
    u16  bdr[2][4][4];
    float acf[2][4];
#pragma unroll
    for (int ni = 0; ni < 4; ++ni) {
        acf[0][ni] = acbh[ni * 16 + lr];
#pragma unroll
        for (int qq = 0; qq < 4; ++qq)
            bdr[0][ni][qq] = bdsp[(i64)qq * T_ + ni * 16 + lr];
    }

    __syncthreads();   // tile 0 k/v ready

    float mrun[4], lrun[4];        // lrun: per-lane partials (reduced once at end)
    f32x4 O[4];
#pragma unroll
    for (int qq = 0; qq < 4; ++qq) { mrun[qq] = -1e30f; lrun[qq] = 0.f; }
#pragma unroll
    for (int ni = 0; ni < 4; ++ni) O[ni] = {0.f, 0.f, 0.f, 0.f};

#pragma unroll
    for (int jt = 0; jt < 8; ++jt) {
        if (jt) __syncthreads();
        const int cur = jt & 1;
        if (jt < 7) {
            int j0n = (jt + 1) * 64;
            const u16* ksrc = qkv + 512 + ((i64)b * T_ + j0n) * QKSTR + h * DK_;
            const u16* vsrc = vT_b + ((i64)(b * H_ + h) * DK_) * T_ + j0n;
#pragma unroll
            for (int t2 = 0; t2 < 2; ++t2) {
                int t = w * 2 + t2;
                gld16(ksrc + (i64)(t * 8 + (lane >> 3)) * QKSTR + lc * 8,
                      (char*)&kbuf[cur ^ 1][0] + t * 1024);
                gld16(vsrc + (i64)(t * 8 + (lane >> 3)) * T_ + lc * 8,
                      (char*)&vbuf[cur ^ 1][0] + t * 1024);
            }
            // issue next tile's bd/acb loads NOW (consumed next iteration)
#pragma unroll
            for (int ni = 0; ni < 4; ++ni) {
                acf[cur ^ 1][ni] = acbh[j0n + ni * 16 + lr];
#pragma unroll
                for (int qq = 0; qq < 4; ++qq)
                    bdr[cur ^ 1][ni][qq] = bdsp[(i64)qq * T_ + j0n + ni * 16 + lr];
            }
        }
        const int j0 = jt * 64;

        f32x4 S[4];
        __builtin_amdgcn_s_setprio(1);
#pragma unroll
        for (int ni = 0; ni < 4; ++ni) {
            int r = ni * 16 + lr;
            bf16x8 kf0 = *reinterpret_cast<const bf16x8*>(
                &kbuf[cur][0] + r * 64 + ((g ^ (r & 7)) * 8));
            bf16x8 kf1 = *reinterpret_cast<const bf16x8*>(
                &kbuf[cur][0] + r * 64 + (((4 + g) ^ (r & 7)) * 8));
            f32x4 acc = {0.f, 0.f, 0.f, 0.f};
            acc = __builtin_amdgcn_mfma_f32_16x16x32_bf16(qw[0], kf0, acc, 0, 0, 0);
            acc = __builtin_amdgcn_mfma_f32_16x16x32_bf16(qw[1], kf1, acc, 0, 0, 0);
            S[ni] = acc;
        }
        __builtin_amdgcn_s_setprio(0);
        // S' = qk*SC2E + acf + bd (all pre-scaled; diagonal bd == 0)
#pragma unroll
        for (int ni = 0; ni < 4; ++ni) {
            int j = j0 + ni * 16 + lr;
#pragma unroll
            for (int qq = 0; qq < 4; ++qq) {
                int rel = j - (i0 + w * 16 + g * 4 + qq);
                float bdv = (rel == 1) ? 0.f : b2f(bdr[cur][ni][qq]);
                S[ni][qq] = fmaf(S[ni][qq], SC2E, acf[cur][ni] + bdv);
            }
        }
        // lazy defer-max: per-lane max only; cross-lane reduce only on growth
        float pl[4];
#pragma unroll
        for (int qq = 0; qq < 4; ++qq)
            pl[qq] = fmaxf(fmaxf(S[0][qq], S[1][qq]), fmaxf(S[2][qq], S[3][qq]));
        bool grow = (pl[0] > mrun[0] + 11.5f) | (pl[1] > mrun[1] + 11.5f)
                  | (pl[2] > mrun[2] + 11.5f) | (pl[3] > mrun[3] + 11.5f);
        if (__any(grow)) {
#pragma unroll
            for (int qq = 0; qq < 4; ++qq) {
                float v0 = pl[qq];
                v0 = fmaxf(v0, __shfl_xor(v0, 1));
                v0 = fmaxf(v0, __shfl_xor(v0, 2));
                v0 = fmaxf(v0, __shfl_xor(v0, 4));
                v0 = fmaxf(v0, __shfl_xor(v0, 8));
                float mnew = fmaxf(mrun[qq], v0);
                float alpha = exp2f(mrun[qq] - mnew);
                mrun[qq] = mnew;
#pragma unroll
                for (int ni = 0; ni < 4; ++ni) O[ni][qq] *= alpha;
                lrun[qq] *= alpha;
            }
        }
        // exp2 + per-lane partial sums
#pragma unroll
        for (int qq = 0; qq < 4; ++qq) {
#pragma unroll
            for (int ni = 0; ni < 4; ++ni) {
                float pv = exp2f(S[ni][qq] - mrun[qq]);
                S[ni][qq] = pv;
                lrun[qq] += pv;
            }
        }
#pragma unroll
        for (int ni = 0; ni < 4; ++ni) {
#pragma unroll
            for (int qq = 0; qq < 4; ++qq) {
                int rp = w * 16 + g * 4 + qq;
                int col = ni * 16 + lr;
                pbuf[rp * 64 + (((col >> 3) ^ (rp & 7)) * 8) + (col & 7)] =
                    f2b(S[ni][qq]);
            }
        }
        __builtin_amdgcn_s_waitcnt(0xC07F);   // lgkmcnt(0)
        __builtin_amdgcn_s_setprio(1);
#pragma unroll
        for (int kk = 0; kk < 2; ++kk) {
            int r = w * 16 + lr;
            bf16x8 aP = *reinterpret_cast<const bf16x8*>(
                &pbuf[0] + r * 64 + (((kk * 4 + g) ^ (r & 7)) * 8));
#pragma unroll
            for (int ni = 0; ni < 4; ++ni) {
                int rv = ni * 16 + lr;
                bf16x8 vf = *reinterpret_cast<const bf16x8*>(
                    &vbuf[cur][0] + rv * 64 + (((kk * 4 + g) ^ (rv & 7)) * 8));
                O[ni] = __builtin_amdgcn_mfma_f32_16x16x32_bf16(aP, vf, O[ni], 0, 0, 0);
            }
        }
        __builtin_amdgcn_s_setprio(0);
    }

    // final cross-lane l-sum reduce (once), then normalize + store
#pragma unroll
    for (int qq = 0; qq < 4; ++qq) {
        float ls = lrun[qq];
        ls += __shfl_xor(ls, 1); ls += __shfl_xor(ls, 2);
        ls += __shfl_xor(ls, 4); ls += __shfl_xor(ls, 8);
        float inv = 1.0f / ls;
        int t = i0 + w * 16 + g * 4 + qq;
        u16* orow = ctx + ((i64)b * T_ + t) * D_ + h * DK_;
#pragma unroll
        for (int ni = 0; ni < 4; ++ni)
            orow[ni * 16 + lr] = f2b(O[ni][qq] * inv);
    }
}

// ---------------------------------------------------------------- MFMA GEMM (NT): C[M,N] = A[M,K] * B[N,K]^T
// 2-phase double-buffered, BK=32, chunk-XOR LDS swizzle (both sides).
// QKVF: q|k -> Cb, v -> vT transposed, acb = (k.pbu)*SC2E reduce.
// BDST: rel_shift scatter of (vv+bias)*SC2E as bf16 (no loads in epilogue).
template<int BN, bool QKVF, bool OUTB, bool BIAS, bool RELU, bool ADD, bool BDST>
__global__ __launch_bounds__(256) void gemm_k(
    const u16* __restrict__ Ag, int lda, i64 sAo, i64 sAi,
    const u16* __restrict__ Bg, int ldb, i64 sBo, i64 sBi,
    void* __restrict__ Cg, int ldc, i64 sCo, i64 sCi,
    const float* __restrict__ biasg, i64 sBiaso, i64 sBiasi,
    const float* __restrict__ adds,
    u16* __restrict__ vTg, float* __restrict__ acbg,
    const float* __restrict__ pbug,
    int innerB, int K)
{
    constexpr int BM   = 128;
    constexpr int WN   = BN / 2;
    constexpr int NFN  = WN / 16;
    constexpr int NISS = (BM + BN) / 64;
    __shared__ u16 sh[2][(BM + BN) * 32];

    int z  = blockIdx.z;
    int ob = z / innerB, ib = z % innerB;
    const u16*   A16 = Ag + ob * sAo + ib * sAi;
    const u16*   Bp  = Bg + ob * sBo + ib * sBi;
    float*       Cf  = (float*)Cg + ob * sCo + ib * sCi;
    u16*         Cb  = (u16*)Cg + ob * sCo + ib * sCi;
    const float* bias = BIAS ? (biasg + ob * sBiaso + ib * sBiasi) : nullptr;
    const float* Asrc = ADD ? (adds + ob * sCo + ib * sCi) : nullptr;

    int tid = threadIdx.x;
    int w = tid >> 6, l = tid & 63;
    int row0 = blockIdx.x * BM, col0 = blockIdx.y * BN;
    int wr = (w >> 1) * 64, wc = (w & 1) * WN;
    int lr = l & 15, g = l >> 4;
    int swz = (lr >> 1) & 3;

    int frb = w * 16 + (l >> 2);
    int cjk = l & 3;

    f32x4 acc[4][NFN];
#pragma unroll
    for (int mi = 0; mi < 4; ++mi)
#pragma unroll
        for (int ni = 0; ni < NFN; ++ni)
#pragma unroll
            for (int j = 0; j < 4; ++j) acc[mi][ni][j] = 0.f;

    const int nt = K / 32;

    auto STAGE = [&](int d, int kt) {
        int k0 = kt * 32;
#pragma unroll
        for (int t = 0; t < NISS; ++t) {
            int R = t * 64 + frb;
            int ccs = (cjk ^ ((R >> 1) & 3)) * 8;
            const u16* src = (R < BM) ? (A16 + (i64)(row0 + R) * lda + k0 + ccs)
                                      : (Bp  + (i64)(col0 + R - BM) * ldb + k0 + ccs);
            gld16(src, (char*)&sh[d][0] + t * 4096 + w * 1024);
        }
    };

    STAGE(0, 0);
    for (int t = 0; t < nt; ++t) {
        const int cur = t & 1;
        __syncthreads();
        if (t + 1 < nt) STAGE(cur ^ 1, t + 1);
        bf16x8 av[4], bv[NFN];
#pragma unroll
        for (int mi = 0; mi < 4; ++mi) {
            int r = wr + mi * 16 + lr;
            av[mi] = *reinterpret_cast<const bf16x8*>(
                (char*)&sh[cur][0] + r * 64 + ((g ^ swz) * 16));
        }
#pragma unroll
        for (int ni = 0; ni < NFN; ++ni) {
            int r = wc + ni * 16 + lr;
            bv[ni] = *reinterpret_cast<const bf16x8*>(
                (char*)&sh[cur][0] + BM * 64 + r * 64 + ((g ^ swz) * 16));
        }
#pragma unroll
        for (int mi = 0; mi < 4; ++mi)
#pragma unroll
            for (int ni = 0; ni < NFN; ++ni)
                acc[mi][ni] = __builtin_amdgcn_mfma_f32_16x16x32_bf16(
                    av[mi], bv[ni], acc[mi][ni], 0, 0, 0);
    }

    if constexpr (QKVF) {
        __shared__ float redbuf[2][64];
        if (col0 >= 1024) {
            int h = (col0 - 1024) >> 6;
#pragma unroll
            for (int mi = 0; mi < 4; ++mi) {
                int r0 = row0 + wr + mi * 16 + g * 4;
                int bb = r0 >> 9, t0 = r0 & 511;
#pragma unroll
                for (int ni = 0; ni < NFN; ++ni) {
                    int d = wc + ni * 16 + lr;
                    u16x4 o;
#pragma unroll
                    for (int q = 0; q < 4; ++q)
                        o[q] = f2b(acc[mi][ni][q] + bias[col0 + d]);
                    *reinterpret_cast<u16x4*>(
                        vTg + ((i64)(bb * 8 + h) * 64 + d) * T_ + t0) = o;
                }
            }
            __syncthreads();
        } else {
            const bool kreg = col0 >= 512;
            int h = (col0 - 512) >> 6;
            float psum[4][4];
#pragma unroll
            for (int mi = 0; mi < 4; ++mi)
#pragma unroll
                for (int q = 0; q < 4; ++q) psum[mi][q] = 0.f;
#pragma unroll
            for (int mi = 0; mi < 4; ++mi) {
#pragma unroll
                for (int ni = 0; ni < NFN; ++ni) {
                    int c = col0 + wc + ni * 16 + lr;
                    float pb = kreg ? pbug[h * 64 + wc + ni * 16 + lr] : 0.f;
#pragma unroll
                    for (int q = 0; q < 4; ++q) {
                        int r = row0 + wr + mi * 16 + g * 4 + q;
                        float vv = acc[mi][ni][q] + bias[c];
                        Cb[(i64)r * QKSTR + c] = f2b(vv);
                        psum[mi][q] += vv * pb;
                    }
                }
            }
            if (kreg) {
#pragma unroll
                for (int mi = 0; mi < 4; ++mi)
#pragma unroll
                    for (int q = 0; q < 4; ++q) {
                        psum[mi][q] += __shfl_xor(psum[mi][q], 1);
                        psum[mi][q] += __shfl_xor(psum[mi][q], 2);
                        psum[mi][q] += __shfl_xor(psum[mi][q], 4);
                        psum[mi][q] += __shfl_xor(psum[mi][q], 8);
                    }
                if ((w & 1) == 1 && lr == 0) {
#pragma unroll
                    for (int mi = 0; mi < 4; ++mi)
#pragma unroll
                        for (int q = 0; q < 4; ++q)
                            redbuf[w >> 1][mi * 16 + g * 4 + q] = psum[mi][q];
                }
            }
            __syncthreads();
            if (kreg && (w & 1) == 0 && lr == 0) {
#pragma unroll
                for (int mi = 0; mi < 4; ++mi)
#pragma unroll
                    for (int q = 0; q < 4; ++q) {
                        int lrow = mi * 16 + g * 4 + q;
                        int r = row0 + wr + lrow;
                        float tot = psum[mi][q] + redbuf[w >> 1][lrow];
                        acbg[(i64)(r >> 9) * 4096 + h * 512 + (r & 511)] = tot * SC2E;
                    }
            }
        }
    } else {
#pragma unroll
        for (int mi = 0; mi < 4; ++mi) {
#pragma unroll
            for (int ni = 0; ni < NFN; ++ni) {
#pragma unroll
                for (int q = 0; q < 4; ++q) {
                    int r = row0 + wr + mi * 16 + g * 4 + q;
                    int c = col0 + wc + ni * 16 + lr;
                    float vv = acc[mi][ni][q];
                    if (BIAS) vv += bias[c];
                    if (BDST) {
                        float sv = vv * SC2E;
                        if (c >= T_ - 1 - r)
                            Cb[(i64)r * T_ + (c - (T_ - 1) + r)] = f2b(sv);
                        else if (r >= 1)
                            Cb[(i64)(r - 1) * T_ + (c + r + 1)] = f2b(sv);
                    } else {
                        if (ADD)  vv += Asrc[(i64)r * ldc + c];
                        if (RELU) vv = vv > 0.f ? vv : 0.f;
                        if (OUTB) Cb[(i64)r * ldc + c] = f2b(vv);
                        else      Cf[(i64)r * ldc + c] = vv;
                    }
                }
            }
        }
    }
}

// ---------------------------------------------------------------- launch
extern "C" void kernel_launch(void* const* d_in, const int* in_sizes, int n_in,
                              void* d_out, int out_size, void* d_ws, size_t ws_size,
                              hipStream_t stream)
{
    const float* xs        = (const float*)d_in[1];
    const float* pos_emb   = (const float*)d_in[2];
    const float* ln_mha_w  = (const float*)d_in[3];
    const float* ln_mha_b  = (const float*)d_in[4];
    const float* wq        = (const float*)d_in[5];
    const float* bq        = (const float*)d_in[6];
    const float* wk        = (const float*)d_in[7];
    const float* bk        = (const float*)d_in[8];
    const float* wv        = (const float*)d_in[9];
    const float* bv        = (const float*)d_in[10];
    const float* wp        = (const float*)d_in[11];
    const float* pbu       = (const float*)d_in[12];
    const float* pbv       = (const float*)d_in[13];
    const float* wo        = (const float*)d_in[14];
    const float* bo        = (const float*)d_in[15];
    const float* ln_ff_w   = (const float*)d_in[16];
    const float* ln_ff_b   = (const float*)d_in[17];
    const float* w1        = (const float*)d_in[18];
    const float* b1        = (const float*)d_in[19];
    const float* w2        = (const float*)d_in[20];
    const float* b2        = (const float*)d_in[21];
    const float* anw       = (const float*)d_in[22];
    const float* anb       = (const float*)d_in[23];

    const i64 NTOK = (i64)B_ * T_;
    const i64 XSZ  = NTOK * D_;

    float* ws = (float*)d_ws;
    i64 off = 0;
    float* x    = ws + off;            off += XSZ;
    u16*  h_b   = (u16*)(ws + off);    off += NTOK * DF_ / 2;
    u16*  bds   = (u16*)(ws + off);    off += (i64)B_*H_*T_*T_/2;
    u16*  qk    = (u16*)(ws + off);    off += NTOK * QKSTR / 2;
    u16*  xn_b  = (u16*)(ws + off);    off += XSZ / 2;
    u16*  vT_b  = (u16*)(ws + off);    off += XSZ / 2;
    u16*  p_all = (u16*)(ws + off);    off += (i64)L_*T_*D_ / 2;
    u16*  pos_b = (u16*)(ws + off);    off += (i64)T_*D_ / 2;
    u16*  wl_b  = (u16*)(ws + off);    off += (i64)L_ * WLSTRIDE / 2;
    float* acb  = ws + off;            off += (i64)B_*H_*T_;
    float* bdb  = ws + off;            off += (i64)L_*H_*T_;
    float* bqkv = ws + off;            off += (i64)L_*1536;

    dim3 blk(256);
    dim3 gLN(2048);
    dim3 gQKV(64, 24, 1);
    dim3 gN64(64, 8, 1);
    dim3 gP(4, 4, 4);
    dim3 gBD(4, 4, 128);
    dim3 gFA(1024, 1, 1);
    dim3 gFF1(64, 16, 1);

    const i64 sBT = (i64)T_ * QKSTR;

    cvt1_k<<<256, blk, 0, stream>>>(pos_emb, pos_b, 65536);
    cvt7_k<<<dim3(3328, 4), blk, 0, stream>>>(wq, wk, wv, wp, wo, w1, w2, wl_b);
    packb_k<<<24, blk, 0, stream>>>(bq, bk, bv, bqkv);

    gemm_k<128,false,true,false,false,false,false><<<gP, blk, 0, stream>>>(
        pos_b, D_, 0, 0, wl_b + 786432, D_, WLSTRIDE, 0,
        p_all, D_, (i64)T_*D_, 0, nullptr, 0, 0,
        nullptr, nullptr, nullptr, nullptr, 1, D_);
    for (int l = 0; l < L_; l++)
        colbias_k<<<128, blk, 0, stream>>>(
            p_all + (i64)l*T_*D_, D_, pbv + (i64)l*H_*DK_, bdb + (i64)l*H_*T_, T_);

    for (int l = 0; l < L_; l++) {
        u16* wl = wl_b + (i64)l * WLSTRIDE;
        const float* xin = (l == 0) ? xs : x;

        ln_k<true><<<gLN, blk, 0, stream>>>(xin, ln_mha_w + l*D_, ln_mha_b + l*D_, xn_b, (int)NTOK);

        gemm_k<64,true,false,true,false,false,false><<<gQKV, blk, 0, stream>>>(
            xn_b, D_, 0, 0, wl + 0, D_, 0, 0, qk, QKSTR, 0, 0,
            bqkv + l*1536, 0, 0, nullptr, vT_b, acb, pbu + (i64)l*H_*DK_, 1, D_);

        gemm_k<128,false,false,true,false,false,true><<<gBD, blk, 0, stream>>>(
            qk, QKSTR, sBT, DK_, p_all + (i64)l*T_*D_, D_, 0, DK_,
            bds, T_, (i64)H_ * T_ * T_, (i64)T_ * T_,
            bdb + (i64)l*H_*T_, 0, T_, nullptr, nullptr, nullptr, nullptr, H_, DK_);

        fattn_k<<<gFA, blk, 0, stream>>>(qk, vT_b, acb, bds, xn_b);

        gemm_k<64,false,false,true,false,true,false><<<gN64, blk, 0, stream>>>(
            xn_b, D_, 0, 0, wl + 1048576, D_, 0, 0, x, D_, 0, 0,
            bo + l*D_, 0, 0, xin, nullptr, nullptr, nullptr, 1, D_);

        ln_k<true><<<gLN, blk, 0, stream>>>(x, ln_ff_w + l*D_, ln_ff_b + l*D_, xn_b, (int)NTOK);

        gemm_k<128,false,true,true,true,false,false><<<gFF1, blk, 0, stream>>>(
            xn_b, D_, 0, 0, wl + 1310720, D_, 0, 0, h_b, DF_, 0, 0,
            b1 + l*DF_, 0, 0, nullptr, nullptr, nullptr, nullptr, 1, D_);
        gemm_k<64,false,false,true,false,true,false><<<gN64, blk, 0, stream>>>(
            h_b, DF_, 0, 0, wl + 2359296, DF_, 0, 0, x, D_, 0, 0,
            b2 + l*D_, 0, 0, x, nullptr, nullptr, nullptr, 1, DF_);
    }

    ln_k<false><<<gLN, blk, 0, stream>>>(x, anw, anb, d_out, (int)NTOK);
}

// Round 16
// 704.453 us; speedup vs baseline: 1.0940x; 1.0940x over previous
//
#include <hip/hip_runtime.h>

typedef long long i64;
typedef unsigned short u16;
typedef __attribute__((ext_vector_type(8))) short bf16x8;
typedef __attribute__((ext_vector_type(8))) unsigned short u16x8;
typedef __attribute__((ext_vector_type(4))) unsigned short u16x4;
typedef __attribute__((ext_vector_type(4))) float f32x4;

#define L_  4
#define B_  16
#define T_  512
#define D_  512
#define H_  8
#define DK_ 64
#define DF_ 2048
#define QKSTR 1024         // q|k row stride (u16); v goes straight to vT

#define WLSTRIDE 3407872   // per-layer bf16 weight count (u16)
#define SC2E 0.1803368801111f   // 0.125 * log2(e): score scale, exp2 domain

__device__ __forceinline__ u16 f2b(float f) {            // fp32 -> bf16 RNE
    unsigned u = __float_as_uint(f);
    u += 0x7FFF + ((u >> 16) & 1);
    return (u16)(u >> 16);
}
__device__ __forceinline__ float b2f(u16 b) {
    return __uint_as_float(((unsigned)b) << 16);
}
__device__ __forceinline__ void gld16(const void* g, void* l) {
    __builtin_amdgcn_global_load_lds(
        (const __attribute__((address_space(1))) void*)g,
        (__attribute__((address_space(3))) void*)l, 16, 0, 0);
}

// ---------------------------------------------------------------- fp32->bf16 converts
__global__ __launch_bounds__(256) void cvt1_k(const float* __restrict__ s,
                                              u16* __restrict__ d, int n4)
{
    int id = blockIdx.x * 256 + threadIdx.x;
    if (id >= n4) return;
    float4 u = reinterpret_cast<const float4*>(s)[id];
    u16x4 o; o[0] = f2b(u.x); o[1] = f2b(u.y); o[2] = f2b(u.z); o[3] = f2b(u.w);
    *reinterpret_cast<u16x4*>(d + (i64)id * 4) = o;
}

// all 4 layers' 7 weight tensors -> contiguous bf16 buffers (blockIdx.y = layer)
__global__ __launch_bounds__(256) void cvt7_k(
    const float* __restrict__ wq, const float* __restrict__ wk,
    const float* __restrict__ wv, const float* __restrict__ wp,
    const float* __restrict__ wo, const float* __restrict__ w1,
    const float* __restrict__ w2, u16* __restrict__ dst)
{
    int l = blockIdx.y;
    wq += (i64)l * 262144; wk += (i64)l * 262144; wv += (i64)l * 262144;
    wp += (i64)l * 262144; wo += (i64)l * 262144;
    w1 += (i64)l * 1048576; w2 += (i64)l * 1048576;
    dst += (i64)l * WLSTRIDE;
    int id = blockIdx.x * 256 + threadIdx.x;  // unit = 4 elems; total 851968
    if (id >= 851968) return;
    const float* s; i64 doff;
    if (id < 327680) {
        int seg = id >> 16, off = id & 65535;
        s = seg == 0 ? wq : seg == 1 ? wk : seg == 2 ? wv : seg == 3 ? wp : wo;
        s += (i64)off * 4;
        doff = (i64)seg * 262144 + (i64)off * 4;
    } else {
        int id2 = id - 327680;
        int seg = id2 >> 18, off = id2 & 262143;
        s = (seg ? w2 : w1) + (i64)off * 4;
        doff = 1310720 + (i64)seg * 1048576 + (i64)off * 4;
    }
    float4 u = *reinterpret_cast<const float4*>(s);
    u16x4 o; o[0] = f2b(u.x); o[1] = f2b(u.y); o[2] = f2b(u.z); o[3] = f2b(u.w);
    *reinterpret_cast<u16x4*>(dst + doff) = o;
}

// pack per-layer qkv biases into [L][1536] fp32
__global__ __launch_bounds__(256) void packb_k(const float* __restrict__ bq,
                                               const float* __restrict__ bk,
                                               const float* __restrict__ bv,
                                               float* __restrict__ dst)
{
    int id = blockIdx.x * 256 + threadIdx.x;   // L*1536 = 6144
    if (id >= L_ * 1536) return;
    int l = id / 1536, c = id % 1536;
    float v = (c < 512) ? bq[l * 512 + c]
            : (c < 1024) ? bk[l * 512 + c - 512]
                         : bv[l * 512 + c - 1024];
    dst[id] = v;
}

// ---------------------------------------------------------------- LayerNorm
template<bool OB>
__global__ __launch_bounds__(256) void ln_k(const float* __restrict__ x,
                                            const float* __restrict__ w,
                                            const float* __restrict__ b,
                                            void* __restrict__ outv, int nrows)
{
    int wid  = (blockIdx.x * 256 + threadIdx.x) >> 6;
    int lane = threadIdx.x & 63;
    if (wid >= nrows) return;
    const float* xr = x + (i64)wid * D_;
    float4 u = reinterpret_cast<const float4*>(xr)[lane * 2 + 0];
    float4 v = reinterpret_cast<const float4*>(xr)[lane * 2 + 1];
    float s = u.x + u.y + u.z + u.w + v.x + v.y + v.z + v.w;
    float q = u.x*u.x + u.y*u.y + u.z*u.z + u.w*u.w
            + v.x*v.x + v.y*v.y + v.z*v.z + v.w*v.w;
#pragma unroll
    for (int m = 1; m < 64; m <<= 1) { s += __shfl_xor(s, m); q += __shfl_xor(q, m); }
    float mu   = s * (1.0f / D_);
    float var  = q * (1.0f / D_) - mu * mu;
    float rstd = rsqrtf(var + 1e-5f);
    int c0 = lane * 8;
    float o[8];
    o[0] = (u.x - mu) * rstd * w[c0+0] + b[c0+0];
    o[1] = (u.y - mu) * rstd * w[c0+1] + b[c0+1];
    o[2] = (u.z - mu) * rstd * w[c0+2] + b[c0+2];
    o[3] = (u.w - mu) * rstd * w[c0+3] + b[c0+3];
    o[4] = (v.x - mu) * rstd * w[c0+4] + b[c0+4];
    o[5] = (v.y - mu) * rstd * w[c0+5] + b[c0+5];
    o[6] = (v.z - mu) * rstd * w[c0+6] + b[c0+6];
    o[7] = (v.w - mu) * rstd * w[c0+7] + b[c0+7];
    if (OB) {
        u16x8 ob;
#pragma unroll
        for (int i = 0; i < 8; i++) ob[i] = f2b(o[i]);
        *reinterpret_cast<u16x8*>((u16*)outv + (i64)wid * D_ + c0) = ob;
    } else {
        float4 o0 = {o[0], o[1], o[2], o[3]};
        float4 o1 = {o[4], o[5], o[6], o[7]};
        reinterpret_cast<float4*>((float*)outv + (i64)wid * D_)[lane * 2 + 0] = o0;
        reinterpret_cast<float4*>((float*)outv + (i64)wid * D_)[lane * 2 + 1] = o1;
    }
}

// ---------------------------------------------------------------- rank-1 column bias (bdb only)
__global__ __launch_bounds__(256) void colbias_k(const u16* __restrict__ kb, int ld,
                                                 const float* __restrict__ pbias,
                                                 float* __restrict__ out, int ntok)
{
    int wid  = (blockIdx.x * 256 + threadIdx.x) >> 6;
    int l    = threadIdx.x & 63;
    if (wid >= ntok) return;
    int h = l >> 3, d0 = (l & 7) * 8;
    u16x8 kv = *reinterpret_cast<const u16x8*>(kb + (i64)wid * ld + h * 64 + d0);
    float s = 0.f;
#pragma unroll
    for (int i = 0; i < 8; i++) s += b2f(kv[i]) * pbias[h * 64 + d0 + i];
    s += __shfl_xor(s, 1); s += __shfl_xor(s, 2); s += __shfl_xor(s, 4);
    if ((l & 7) == 0) out[(i64)(wid >> 9) * 4096 + h * 512 + (wid & 511)] = s;
}

// ---------------------------------------------------------------- fused attention
// bds pre-shifted and pre-scaled by SC2E; acb pre-scaled at production.
// exp2-domain softmax with lazy pmax reduce + per-lane deferred l-sum.
__global__ __launch_bounds__(256, 4) void fattn_k(
    const u16* __restrict__ qkv, const u16* __restrict__ vT_b,
    const float* __restrict__ acb, const u16* __restrict__ bds,
    u16* __restrict__ ctx)
{
    __shared__ u16 kbuf[2][64 * 64];
    __shared__ u16 vbuf[2][64 * 64];
    __shared__ u16 pbuf[64 * 64];

    const int id = blockIdx.x;
    const int h = id & 7, b = (id >> 3) & 15, qt = id >> 7;
    const int i0 = qt * 64;
    const int tid = threadIdx.x;
    const int w = tid >> 6, lane = tid & 63;
    const int lr = lane & 15, g = lane >> 4;
    const int lc = (lane & 7) ^ ((lane >> 3) & 7);

    bf16x8 qw[2];
#pragma unroll
    for (int kk = 0; kk < 2; ++kk)
        qw[kk] = *reinterpret_cast<const bf16x8*>(
            qkv + ((i64)b * T_ + i0 + w * 16 + lr) * QKSTR + h * DK_ + kk * 32 + g * 8);

    {
        const u16* ksrc = qkv + 512 + ((i64)b * T_) * QKSTR + h * DK_;
        const u16* vsrc = vT_b + ((i64)(b * H_ + h) * DK_) * T_;
#pragma unroll
        for (int t2 = 0; t2 < 2; ++t2) {
            int t = w * 2 + t2;
            gld16(ksrc + (i64)(t * 8 + (lane >> 3)) * QKSTR + lc * 8,
                  (char*)&kbuf[0][0] + t * 1024);
            gld16(vsrc + (i64)(t * 8 + (lane >> 3)) * T_ + lc * 8,
                  (char*)&vbuf[0][0] + t * 1024);
        }
    }
    __syncthreads();

    float mrun[4], lrun[4];        // lrun: PER-LANE partial sums (reduced once at end)
    f32x4 O[4];
#pragma unroll
    for (int qq = 0; qq < 4; ++qq) { mrun[qq] = -1e30f; lrun[qq] = 0.f; }
#pragma unroll
    for (int ni = 0; ni < 4; ++ni) O[ni] = {0.f, 0.f, 0.f, 0.f};

    const float* acbh = acb + (i64)b * (H_ * T_) + h * T_;
    const u16* bdsp = bds + (((i64)(b * H_ + h)) << 18)
                          + (i64)(i0 + w * 16 + g * 4) * T_;

    for (int jt = 0; jt < 8; ++jt) {
        if (jt) __syncthreads();
        const int cur = jt & 1;
        if (jt < 7) {
            int j0n = (jt + 1) * 64;
            const u16* ksrc = qkv + 512 + ((i64)b * T_ + j0n) * QKSTR + h * DK_;
            const u16* vsrc = vT_b + ((i64)(b * H_ + h) * DK_) * T_ + j0n;
#pragma unroll
            for (int t2 = 0; t2 < 2; ++t2) {
                int t = w * 2 + t2;
                gld16(ksrc + (i64)(t * 8 + (lane >> 3)) * QKSTR + lc * 8,
                      (char*)&kbuf[cur ^ 1][0] + t * 1024);
                gld16(vsrc + (i64)(t * 8 + (lane >> 3)) * T_ + lc * 8,
                      (char*)&vbuf[cur ^ 1][0] + t * 1024);
            }
        }
        const int j0 = jt * 64;

        u16 bdr[4][4];
        float acf[4];
#pragma unroll
        for (int ni = 0; ni < 4; ++ni) {
            acf[ni] = acbh[j0 + ni * 16 + lr];   // pre-scaled by SC2E
#pragma unroll
            for (int qq = 0; qq < 4; ++qq)
                bdr[ni][qq] = bdsp[(i64)qq * T_ + j0 + ni * 16 + lr];
        }

        f32x4 S[4];
        __builtin_amdgcn_s_setprio(1);
#pragma unroll
        for (int ni = 0; ni < 4; ++ni) {
            int r = ni * 16 + lr;
            bf16x8 kf0 = *reinterpret_cast<const bf16x8*>(
                &kbuf[cur][0] + r * 64 + ((g ^ (r & 7)) * 8));
            bf16x8 kf1 = *reinterpret_cast<const bf16x8*>(
                &kbuf[cur][0] + r * 64 + (((4 + g) ^ (r & 7)) * 8));
            f32x4 acc = {0.f, 0.f, 0.f, 0.f};
            acc = __builtin_amdgcn_mfma_f32_16x16x32_bf16(qw[0], kf0, acc, 0, 0, 0);
            acc = __builtin_amdgcn_mfma_f32_16x16x32_bf16(qw[1], kf1, acc, 0, 0, 0);
            S[ni] = acc;
        }
        __builtin_amdgcn_s_setprio(0);
        // S' = qk*SC2E + acf + bd (all pre-scaled; diagonal bd == 0)
#pragma unroll
        for (int ni = 0; ni < 4; ++ni) {
            int j = j0 + ni * 16 + lr;
#pragma unroll
            for (int qq = 0; qq < 4; ++qq) {
                int rel = j - (i0 + w * 16 + g * 4 + qq);
                float bdv = (rel == 1) ? 0.f : b2f(bdr[ni][qq]);
                S[ni][qq] = fmaf(S[ni][qq], SC2E, acf[ni] + bdv);
            }
        }
        // lazy defer-max: per-lane max only; cross-lane reduce only on growth
        float pl[4];
#pragma unroll
        for (int qq = 0; qq < 4; ++qq)
            pl[qq] = fmaxf(fmaxf(S[0][qq], S[1][qq]), fmaxf(S[2][qq], S[3][qq]));
        bool grow = (pl[0] > mrun[0] + 11.5f) | (pl[1] > mrun[1] + 11.5f)
                  | (pl[2] > mrun[2] + 11.5f) | (pl[3] > mrun[3] + 11.5f);
        if (__any(grow)) {
#pragma unroll
            for (int qq = 0; qq < 4; ++qq) {
                float v0 = pl[qq];
                v0 = fmaxf(v0, __shfl_xor(v0, 1));
                v0 = fmaxf(v0, __shfl_xor(v0, 2));
                v0 = fmaxf(v0, __shfl_xor(v0, 4));
                v0 = fmaxf(v0, __shfl_xor(v0, 8));
                float mnew = fmaxf(mrun[qq], v0);
                float alpha = exp2f(mrun[qq] - mnew);
                mrun[qq] = mnew;
#pragma unroll
                for (int ni = 0; ni < 4; ++ni) O[ni][qq] *= alpha;
                lrun[qq] *= alpha;       // per-lane partial rescale (uniform alpha)
            }
        }
        // exp2 + per-lane partial sums (NO cross-lane reduce here)
#pragma unroll
        for (int qq = 0; qq < 4; ++qq) {
#pragma unroll
            for (int ni = 0; ni < 4; ++ni) {
                float pv = exp2f(S[ni][qq] - mrun[qq]);
                S[ni][qq] = pv;
                lrun[qq] += pv;
            }
        }
#pragma unroll
        for (int ni = 0; ni < 4; ++ni) {
#pragma unroll
            for (int qq = 0; qq < 4; ++qq) {
                int rp = w * 16 + g * 4 + qq;
                int col = ni * 16 + lr;
                pbuf[rp * 64 + (((col >> 3) ^ (rp & 7)) * 8) + (col & 7)] =
                    f2b(S[ni][qq]);
            }
        }
        __builtin_amdgcn_s_waitcnt(0xC07F);   // lgkmcnt(0)
        __builtin_amdgcn_s_setprio(1);
#pragma unroll
        for (int kk = 0; kk < 2; ++kk) {
            int r = w * 16 + lr;
            bf16x8 aP = *reinterpret_cast<const bf16x8*>(
                &pbuf[0] + r * 64 + (((kk * 4 + g) ^ (r & 7)) * 8));
#pragma unroll
            for (int ni = 0; ni < 4; ++ni) {
                int rv = ni * 16 + lr;
                bf16x8 vf = *reinterpret_cast<const bf16x8*>(
                    &vbuf[cur][0] + rv * 64 + (((kk * 4 + g) ^ (rv & 7)) * 8));
                O[ni] = __builtin_amdgcn_mfma_f32_16x16x32_bf16(aP, vf, O[ni], 0, 0, 0);
            }
        }
        __builtin_amdgcn_s_setprio(0);
    }

    // final cross-lane l-sum reduce (once), then normalize + store
#pragma unroll
    for (int qq = 0; qq < 4; ++qq) {
        float ls = lrun[qq];
        ls += __shfl_xor(ls, 1); ls += __shfl_xor(ls, 2);
        ls += __shfl_xor(ls, 4); ls += __shfl_xor(ls, 8);
        float inv = 1.0f / ls;
        int t = i0 + w * 16 + g * 4 + qq;
        u16* orow = ctx + ((i64)b * T_ + t) * D_ + h * DK_;
#pragma unroll
        for (int ni = 0; ni < 4; ++ni)
            orow[ni * 16 + lr] = f2b(O[ni][qq] * inv);
    }
}

// ---------------------------------------------------------------- MFMA GEMM (NT): C[M,N] = A[M,K] * B[N,K]^T
// 2-phase double-buffered, BK=32, chunk-XOR LDS swizzle (both sides).
// QKVF: q|k -> Cb, v -> vT transposed, acb = (k.pbu)*SC2E reduce.
// BDST: rel_shift scatter of (vv+bias)*SC2E as bf16 (no loads in epilogue).
template<int BN, bool QKVF, bool OUTB, bool BIAS, bool RELU, bool ADD, bool BDST>
__global__ __launch_bounds__(256) void gemm_k(
    const u16* __restrict__ Ag, int lda, i64 sAo, i64 sAi,
    const u16* __restrict__ Bg, int ldb, i64 sBo, i64 sBi,
    void* __restrict__ Cg, int ldc, i64 sCo, i64 sCi,
    const float* __restrict__ biasg, i64 sBiaso, i64 sBiasi,
    const float* __restrict__ adds,
    u16* __restrict__ vTg, float* __restrict__ acbg,
    const float* __restrict__ pbug,
    int innerB, int K)
{
    constexpr int BM   = 128;
    constexpr int WN   = BN / 2;
    constexpr int NFN  = WN / 16;
    constexpr int NISS = (BM + BN) / 64;
    __shared__ u16 sh[2][(BM + BN) * 32];

    int z  = blockIdx.z;
    int ob = z / innerB, ib = z % innerB;
    const u16*   A16 = Ag + ob * sAo + ib * sAi;
    const u16*   Bp  = Bg + ob * sBo + ib * sBi;
    float*       Cf  = (float*)Cg + ob * sCo + ib * sCi;
    u16*         Cb  = (u16*)Cg + ob * sCo + ib * sCi;
    const float* bias = BIAS ? (biasg + ob * sBiaso + ib * sBiasi) : nullptr;
    const float* Asrc = ADD ? (adds + ob * sCo + ib * sCi) : nullptr;

    int tid = threadIdx.x;
    int w = tid >> 6, l = tid & 63;
    int row0 = blockIdx.x * BM, col0 = blockIdx.y * BN;
    int wr = (w >> 1) * 64, wc = (w & 1) * WN;
    int lr = l & 15, g = l >> 4;
    int swz = (lr >> 1) & 3;

    int frb = w * 16 + (l >> 2);
    int cjk = l & 3;

    f32x4 acc[4][NFN];
#pragma unroll
    for (int mi = 0; mi < 4; ++mi)
#pragma unroll
        for (int ni = 0; ni < NFN; ++ni)
#pragma unroll
            for (int j = 0; j < 4; ++j) acc[mi][ni][j] = 0.f;

    const int nt = K / 32;

    auto STAGE = [&](int d, int kt) {
        int k0 = kt * 32;
#pragma unroll
        for (int t = 0; t < NISS; ++t) {
            int R = t * 64 + frb;
            int ccs = (cjk ^ ((R >> 1) & 3)) * 8;
            const u16* src = (R < BM) ? (A16 + (i64)(row0 + R) * lda + k0 + ccs)
                                      : (Bp  + (i64)(col0 + R - BM) * ldb + k0 + ccs);
            gld16(src, (char*)&sh[d][0] + t * 4096 + w * 1024);
        }
    };

    STAGE(0, 0);
    for (int t = 0; t < nt; ++t) {
        const int cur = t & 1;
        __syncthreads();
        if (t + 1 < nt) STAGE(cur ^ 1, t + 1);
        bf16x8 av[4], bv[NFN];
#pragma unroll
        for (int mi = 0; mi < 4; ++mi) {
            int r = wr + mi * 16 + lr;
            av[mi] = *reinterpret_cast<const bf16x8*>(
                (char*)&sh[cur][0] + r * 64 + ((g ^ swz) * 16));
        }
#pragma unroll
        for (int ni = 0; ni < NFN; ++ni) {
            int r = wc + ni * 16 + lr;
            bv[ni] = *reinterpret_cast<const bf16x8*>(
                (char*)&sh[cur][0] + BM * 64 + r * 64 + ((g ^ swz) * 16));
        }
#pragma unroll
        for (int mi = 0; mi < 4; ++mi)
#pragma unroll
            for (int ni = 0; ni < NFN; ++ni)
                acc[mi][ni] = __builtin_amdgcn_mfma_f32_16x16x32_bf16(
                    av[mi], bv[ni], acc[mi][ni], 0, 0, 0);
    }

    if constexpr (QKVF) {
        __shared__ float redbuf[2][64];
        if (col0 >= 1024) {
            int h = (col0 - 1024) >> 6;
#pragma unroll
            for (int mi = 0; mi < 4; ++mi) {
                int r0 = row0 + wr + mi * 16 + g * 4;
                int bb = r0 >> 9, t0 = r0 & 511;
#pragma unroll
                for (int ni = 0; ni < NFN; ++ni) {
                    int d = wc + ni * 16 + lr;
                    u16x4 o;
#pragma unroll
                    for (int q = 0; q < 4; ++q)
                        o[q] = f2b(acc[mi][ni][q] + bias[col0 + d]);
                    *reinterpret_cast<u16x4*>(
                        vTg + ((i64)(bb * 8 + h) * 64 + d) * T_ + t0) = o;
                }
            }
            __syncthreads();
        } else {
            const bool kreg = col0 >= 512;
            int h = (col0 - 512) >> 6;
            float psum[4][4];
#pragma unroll
            for (int mi = 0; mi < 4; ++mi)
#pragma unroll
                for (int q = 0; q < 4; ++q) psum[mi][q] = 0.f;
#pragma unroll
            for (int mi = 0; mi < 4; ++mi) {
#pragma unroll
                for (int ni = 0; ni < NFN; ++ni) {
                    int c = col0 + wc + ni * 16 + lr;
                    float pb = kreg ? pbug[h * 64 + wc + ni * 16 + lr] : 0.f;
#pragma unroll
                    for (int q = 0; q < 4; ++q) {
                        int r = row0 + wr + mi * 16 + g * 4 + q;
                        float vv = acc[mi][ni][q] + bias[c];
                        Cb[(i64)r * QKSTR + c] = f2b(vv);
                        psum[mi][q] += vv * pb;
                    }
                }
            }
            if (kreg) {
#pragma unroll
                for (int mi = 0; mi < 4; ++mi)
#pragma unroll
                    for (int q = 0; q < 4; ++q) {
                        psum[mi][q] += __shfl_xor(psum[mi][q], 1);
                        psum[mi][q] += __shfl_xor(psum[mi][q], 2);
                        psum[mi][q] += __shfl_xor(psum[mi][q], 4);
                        psum[mi][q] += __shfl_xor(psum[mi][q], 8);
                    }
                if ((w & 1) == 1 && lr == 0) {
#pragma unroll
                    for (int mi = 0; mi < 4; ++mi)
#pragma unroll
                        for (int q = 0; q < 4; ++q)
                            redbuf[w >> 1][mi * 16 + g * 4 + q] = psum[mi][q];
                }
            }
            __syncthreads();
            if (kreg && (w & 1) == 0 && lr == 0) {
#pragma unroll
                for (int mi = 0; mi < 4; ++mi)
#pragma unroll
                    for (int q = 0; q < 4; ++q) {
                        int lrow = mi * 16 + g * 4 + q;
                        int r = row0 + wr + lrow;
                        float tot = psum[mi][q] + redbuf[w >> 1][lrow];
                        acbg[(i64)(r >> 9) * 4096 + h * 512 + (r & 511)] = tot * SC2E;
                    }
            }
        }
    } else {
#pragma unroll
        for (int mi = 0; mi < 4; ++mi) {
#pragma unroll
            for (int ni = 0; ni < NFN; ++ni) {
#pragma unroll
                for (int q = 0; q < 4; ++q) {
                    int r = row0 + wr + mi * 16 + g * 4 + q;
                    int c = col0 + wc + ni * 16 + lr;
                    float vv = acc[mi][ni][q];
                    if (BIAS) vv += bias[c];
                    if (BDST) {
                        float sv = vv * SC2E;
                        if (c >= T_ - 1 - r)
                            Cb[(i64)r * T_ + (c - (T_ - 1) + r)] = f2b(sv);
                        else if (r >= 1)
                            Cb[(i64)(r - 1) * T_ + (c + r + 1)] = f2b(sv);
                    } else {
                        if (ADD)  vv += Asrc[(i64)r * ldc + c];
                        if (RELU) vv = vv > 0.f ? vv : 0.f;
                        if (OUTB) Cb[(i64)r * ldc + c] = f2b(vv);
                        else      Cf[(i64)r * ldc + c] = vv;
                    }
                }
            }
        }
    }
}

// ---------------------------------------------------------------- launch
extern "C" void kernel_launch(void* const* d_in, const int* in_sizes, int n_in,
                              void* d_out, int out_size, void* d_ws, size_t ws_size,
                              hipStream_t stream)
{
    const float* xs        = (const float*)d_in[1];
    const float* pos_emb   = (const float*)d_in[2];
    const float* ln_mha_w  = (const float*)d_in[3];
    const float* ln_mha_b  = (const float*)d_in[4];
    const float* wq        = (const float*)d_in[5];
    const float* bq        = (const float*)d_in[6];
    const float* wk        = (const float*)d_in[7];
    const float* bk        = (const float*)d_in[8];
    const float* wv        = (const float*)d_in[9];
    const float* bv        = (const float*)d_in[10];
    const float* wp        = (const float*)d_in[11];
    const float* pbu       = (const float*)d_in[12];
    const float* pbv       = (const float*)d_in[13];
    const float* wo        = (const float*)d_in[14];
    const float* bo        = (const float*)d_in[15];
    const float* ln_ff_w   = (const float*)d_in[16];
    const float* ln_ff_b   = (const float*)d_in[17];
    const float* w1        = (const float*)d_in[18];
    const float* b1        = (const float*)d_in[19];
    const float* w2        = (const float*)d_in[20];
    const float* b2        = (const float*)d_in[21];
    const float* anw       = (const float*)d_in[22];
    const float* anb       = (const float*)d_in[23];

    const i64 NTOK = (i64)B_ * T_;
    const i64 XSZ  = NTOK * D_;

    float* ws = (float*)d_ws;
    i64 off = 0;
    float* x    = ws + off;            off += XSZ;
    u16*  h_b   = (u16*)(ws + off);    off += NTOK * DF_ / 2;
    u16*  bds   = (u16*)(ws + off);    off += (i64)B_*H_*T_*T_/2;
    u16*  qk    = (u16*)(ws + off);    off += NTOK * QKSTR / 2;
    u16*  xn_b  = (u16*)(ws + off);    off += XSZ / 2;
    u16*  vT_b  = (u16*)(ws + off);    off += XSZ / 2;
    u16*  p_all = (u16*)(ws + off);    off += (i64)L_*T_*D_ / 2;
    u16*  pos_b = (u16*)(ws + off);    off += (i64)T_*D_ / 2;
    u16*  wl_b  = (u16*)(ws + off);    off += (i64)L_ * WLSTRIDE / 2;
    float* acb  = ws + off;            off += (i64)B_*H_*T_;
    float* bdb  = ws + off;            off += (i64)L_*H_*T_;
    float* bqkv = ws + off;            off += (i64)L_*1536;

    dim3 blk(256);
    dim3 gLN(2048);
    dim3 gQKV(64, 24, 1);
    dim3 gN64(64, 8, 1);
    dim3 gP(4, 4, 4);
    dim3 gBD(4, 4, 128);
    dim3 gFA(1024, 1, 1);
    dim3 gFF1(64, 16, 1);

    const i64 sBT = (i64)T_ * QKSTR;

    cvt1_k<<<256, blk, 0, stream>>>(pos_emb, pos_b, 65536);
    cvt7_k<<<dim3(3328, 4), blk, 0, stream>>>(wq, wk, wv, wp, wo, w1, w2, wl_b);
    packb_k<<<24, blk, 0, stream>>>(bq, bk, bv, bqkv);

    gemm_k<128,false,true,false,false,false,false><<<gP, blk, 0, stream>>>(
        pos_b, D_, 0, 0, wl_b + 786432, D_, WLSTRIDE, 0,
        p_all, D_, (i64)T_*D_, 0, nullptr, 0, 0,
        nullptr, nullptr, nullptr, nullptr, 1, D_);
    for (int l = 0; l < L_; l++)
        colbias_k<<<128, blk, 0, stream>>>(
            p_all + (i64)l*T_*D_, D_, pbv + (i64)l*H_*DK_, bdb + (i64)l*H_*T_, T_);

    for (int l = 0; l < L_; l++) {
        u16* wl = wl_b + (i64)l * WLSTRIDE;
        const float* xin = (l == 0) ? xs : x;

        ln_k<true><<<gLN, blk, 0, stream>>>(xin, ln_mha_w + l*D_, ln_mha_b + l*D_, xn_b, (int)NTOK);

        gemm_k<64,true,false,true,false,false,false><<<gQKV, blk, 0, stream>>>(
            xn_b, D_, 0, 0, wl + 0, D_, 0, 0, qk, QKSTR, 0, 0,
            bqkv + l*1536, 0, 0, nullptr, vT_b, acb, pbu + (i64)l*H_*DK_, 1, D_);

        gemm_k<128,false,false,true,false,false,true><<<gBD, blk, 0, stream>>>(
            qk, QKSTR, sBT, DK_, p_all + (i64)l*T_*D_, D_, 0, DK_,
            bds, T_, (i64)H_ * T_ * T_, (i64)T_ * T_,
            bdb + (i64)l*H_*T_, 0, T_, nullptr, nullptr, nullptr, nullptr, H_, DK_);

        fattn_k<<<gFA, blk, 0, stream>>>(qk, vT_b, acb, bds, xn_b);

        gemm_k<64,false,false,true,false,true,false><<<gN64, blk, 0, stream>>>(
            xn_b, D_, 0, 0, wl + 1048576, D_, 0, 0, x, D_, 0, 0,
            bo + l*D_, 0, 0, xin, nullptr, nullptr, nullptr, 1, D_);

        ln_k<true><<<gLN, blk, 0, stream>>>(x, ln_ff_w + l*D_, ln_ff_b + l*D_, xn_b, (int)NTOK);

        gemm_k<128,false,true,true,true,false,false><<<gFF1, blk, 0, stream>>>(
            xn_b, D_, 0, 0, wl + 1310720, D_, 0, 0, h_b, DF_, 0, 0,
            b1 + l*DF_, 0, 0, nullptr, nullptr, nullptr, nullptr, 1, D_);
        gemm_k<64,false,false,true,false,true,false><<<gN64, blk, 0, stream>>>(
            h_b, DF_, 0, 0, wl + 2359296, DF_, 0, 0, x, D_, 0, 0,
            b2 + l*D_, 0, 0, x, nullptr, nullptr, nullptr, 1, DF_);
    }

    ln_k<false><<<gLN, blk, 0, stream>>>(x, anw, anb, d_out, (int)NTOK);
}

// Round 17
// 690.595 us; speedup vs baseline: 1.1160x; 1.0201x over previous
//
#include <hip/hip_runtime.h>

typedef long long i64;
typedef unsigned short u16;
typedef __attribute__((ext_vector_type(8))) short bf16x8;
typedef __attribute__((ext_vector_type(8))) unsigned short u16x8;
typedef __attribute__((ext_vector_type(4))) unsigned short u16x4;
typedef __attribute__((ext_vector_type(4))) float f32x4;

#define L_  4
#define B_  16
#define T_  512
#define D_  512
#define H_  8
#define DK_ 64
#define DF_ 2048
#define QKSTR 1024         // q|k row stride (u16); v goes straight to vT

#define WLSTRIDE 3407872   // per-layer bf16 weight count (u16)
#define SC2E 0.1803368801111f   // 0.125 * log2(e): score scale, exp2 domain

__device__ __forceinline__ u16 f2b(float f) {            // fp32 -> bf16 RNE
    unsigned u = __float_as_uint(f);
    u += 0x7FFF + ((u >> 16) & 1);
    return (u16)(u >> 16);
}
__device__ __forceinline__ float b2f(u16 b) {
    return __uint_as_float(((unsigned)b) << 16);
}
__device__ __forceinline__ void gld16(const void* g, void* l) {
    __builtin_amdgcn_global_load_lds(
        (const __attribute__((address_space(1))) void*)g,
        (__attribute__((address_space(3))) void*)l, 16, 0, 0);
}

// ---------------------------------------------------------------- fp32->bf16 converts
__global__ __launch_bounds__(256) void cvt1_k(const float* __restrict__ s,
                                              u16* __restrict__ d, int n4)
{
    int id = blockIdx.x * 256 + threadIdx.x;
    if (id >= n4) return;
    float4 u = reinterpret_cast<const float4*>(s)[id];
    u16x4 o; o[0] = f2b(u.x); o[1] = f2b(u.y); o[2] = f2b(u.z); o[3] = f2b(u.w);
    *reinterpret_cast<u16x4*>(d + (i64)id * 4) = o;
}

// all 4 layers' 7 weight tensors -> contiguous bf16 buffers (blockIdx.y = layer)
__global__ __launch_bounds__(256) void cvt7_k(
    const float* __restrict__ wq, const float* __restrict__ wk,
    const float* __restrict__ wv, const float* __restrict__ wp,
    const float* __restrict__ wo, const float* __restrict__ w1,
    const float* __restrict__ w2, u16* __restrict__ dst)
{
    int l = blockIdx.y;
    wq += (i64)l * 262144; wk += (i64)l * 262144; wv += (i64)l * 262144;
    wp += (i64)l * 262144; wo += (i64)l * 262144;
    w1 += (i64)l * 1048576; w2 += (i64)l * 1048576;
    dst += (i64)l * WLSTRIDE;
    int id = blockIdx.x * 256 + threadIdx.x;  // unit = 4 elems; total 851968
    if (id >= 851968) return;
    const float* s; i64 doff;
    if (id < 327680) {
        int seg = id >> 16, off = id & 65535;
        s = seg == 0 ? wq : seg == 1 ? wk : seg == 2 ? wv : seg == 3 ? wp : wo;
        s += (i64)off * 4;
        doff = (i64)seg * 262144 + (i64)off * 4;
    } else {
        int id2 = id - 327680;
        int seg = id2 >> 18, off = id2 & 262143;
        s = (seg ? w2 : w1) + (i64)off * 4;
        doff = 1310720 + (i64)seg * 1048576 + (i64)off * 4;
    }
    float4 u = *reinterpret_cast<const float4*>(s);
    u16x4 o; o[0] = f2b(u.x); o[1] = f2b(u.y); o[2] = f2b(u.z); o[3] = f2b(u.w);
    *reinterpret_cast<u16x4*>(dst + doff) = o;
}

// pack per-layer qkv biases into [L][1536] fp32
__global__ __launch_bounds__(256) void packb_k(const float* __restrict__ bq,
                                               const float* __restrict__ bk,
                                               const float* __restrict__ bv,
                                               float* __restrict__ dst)
{
    int id = blockIdx.x * 256 + threadIdx.x;   // L*1536 = 6144
    if (id >= L_ * 1536) return;
    int l = id / 1536, c = id % 1536;
    float v = (c < 512) ? bq[l * 512 + c]
            : (c < 1024) ? bk[l * 512 + c - 512]
                         : bv[l * 512 + c - 1024];
    dst[id] = v;
}

// ---------------------------------------------------------------- LayerNorm
template<bool OB>
__global__ __launch_bounds__(256) void ln_k(const float* __restrict__ x,
                                            const float* __restrict__ w,
                                            const float* __restrict__ b,
                                            void* __restrict__ outv, int nrows)
{
    int wid  = (blockIdx.x * 256 + threadIdx.x) >> 6;
    int lane = threadIdx.x & 63;
    if (wid >= nrows) return;
    const float* xr = x + (i64)wid * D_;
    float4 u = reinterpret_cast<const float4*>(xr)[lane * 2 + 0];
    float4 v = reinterpret_cast<const float4*>(xr)[lane * 2 + 1];
    float s = u.x + u.y + u.z + u.w + v.x + v.y + v.z + v.w;
    float q = u.x*u.x + u.y*u.y + u.z*u.z + u.w*u.w
            + v.x*v.x + v.y*v.y + v.z*v.z + v.w*v.w;
#pragma unroll
    for (int m = 1; m < 64; m <<= 1) { s += __shfl_xor(s, m); q += __shfl_xor(q, m); }
    float mu   = s * (1.0f / D_);
    float var  = q * (1.0f / D_) - mu * mu;
    float rstd = rsqrtf(var + 1e-5f);
    int c0 = lane * 8;
    float o[8];
    o[0] = (u.x - mu) * rstd * w[c0+0] + b[c0+0];
    o[1] = (u.y - mu) * rstd * w[c0+1] + b[c0+1];
    o[2] = (u.z - mu) * rstd * w[c0+2] + b[c0+2];
    o[3] = (u.w - mu) * rstd * w[c0+3] + b[c0+3];
    o[4] = (v.x - mu) * rstd * w[c0+4] + b[c0+4];
    o[5] = (v.y - mu) * rstd * w[c0+5] + b[c0+5];
    o[6] = (v.z - mu) * rstd * w[c0+6] + b[c0+6];
    o[7] = (v.w - mu) * rstd * w[c0+7] + b[c0+7];
    if (OB) {
        u16x8 ob;
#pragma unroll
        for (int i = 0; i < 8; i++) ob[i] = f2b(o[i]);
        *reinterpret_cast<u16x8*>((u16*)outv + (i64)wid * D_ + c0) = ob;
    } else {
        float4 o0 = {o[0], o[1], o[2], o[3]};
        float4 o1 = {o[4], o[5], o[6], o[7]};
        reinterpret_cast<float4*>((float*)outv + (i64)wid * D_)[lane * 2 + 0] = o0;
        reinterpret_cast<float4*>((float*)outv + (i64)wid * D_)[lane * 2 + 1] = o1;
    }
}

// ---------------------------------------------------------------- rank-1 column bias (bdb only)
__global__ __launch_bounds__(256) void colbias_k(const u16* __restrict__ kb, int ld,
                                                 const float* __restrict__ pbias,
                                                 float* __restrict__ out, int ntok)
{
    int wid  = (blockIdx.x * 256 + threadIdx.x) >> 6;
    int l    = threadIdx.x & 63;
    if (wid >= ntok) return;
    int h = l >> 3, d0 = (l & 7) * 8;
    u16x8 kv = *reinterpret_cast<const u16x8*>(kb + (i64)wid * ld + h * 64 + d0);
    float s = 0.f;
#pragma unroll
    for (int i = 0; i < 8; i++) s += b2f(kv[i]) * pbias[h * 64 + d0 + i];
    s += __shfl_xor(s, 1); s += __shfl_xor(s, 2); s += __shfl_xor(s, 4);
    if ((l & 7) == 0) out[(i64)(wid >> 9) * 4096 + h * 512 + (wid & 511)] = s;
}

// ---------------------------------------------------------------- fused attention
// bds pre-shifted and pre-scaled by SC2E; acb pre-scaled at production.
// exp2-domain softmax with lazy pmax reduce + per-lane deferred l-sum.
// b decode REVERSED so the most-recently-written bds batches (still in the
// head-local XCD L2) are read first.
__global__ __launch_bounds__(256, 4) void fattn_k(
    const u16* __restrict__ qkv, const u16* __restrict__ vT_b,
    const float* __restrict__ acb, const u16* __restrict__ bds,
    u16* __restrict__ ctx)
{
    __shared__ u16 kbuf[2][64 * 64];
    __shared__ u16 vbuf[2][64 * 64];
    __shared__ u16 pbuf[64 * 64];

    const int id = blockIdx.x;
    const int h = id & 7, b = 15 - ((id >> 3) & 15), qt = id >> 7;
    const int i0 = qt * 64;
    const int tid = threadIdx.x;
    const int w = tid >> 6, lane = tid & 63;
    const int lr = lane & 15, g = lane >> 4;
    const int lc = (lane & 7) ^ ((lane >> 3) & 7);

    bf16x8 qw[2];
#pragma unroll
    for (int kk = 0; kk < 2; ++kk)
        qw[kk] = *reinterpret_cast<const bf16x8*>(
            qkv + ((i64)b * T_ + i0 + w * 16 + lr) * QKSTR + h * DK_ + kk * 32 + g * 8);

    {
        const u16* ksrc = qkv + 512 + ((i64)b * T_) * QKSTR + h * DK_;
        const u16* vsrc = vT_b + ((i64)(b * H_ + h) * DK_) * T_;
#pragma unroll
        for (int t2 = 0; t2 < 2; ++t2) {
            int t = w * 2 + t2;
            gld16(ksrc + (i64)(t * 8 + (lane >> 3)) * QKSTR + lc * 8,
                  (char*)&kbuf[0][0] + t * 1024);
            gld16(vsrc + (i64)(t * 8 + (lane >> 3)) * T_ + lc * 8,
                  (char*)&vbuf[0][0] + t * 1024);
        }
    }
    __syncthreads();

    float mrun[4], lrun[4];        // lrun: PER-LANE partial sums (reduced once at end)
    f32x4 O[4];
#pragma unroll
    for (int qq = 0; qq < 4; ++qq) { mrun[qq] = -1e30f; lrun[qq] = 0.f; }
#pragma unroll
    for (int ni = 0; ni < 4; ++ni) O[ni] = {0.f, 0.f, 0.f, 0.f};

    const float* acbh = acb + (i64)b * (H_ * T_) + h * T_;
    const u16* bdsp = bds + (((i64)(b * H_ + h)) << 18)
                          + (i64)(i0 + w * 16 + g * 4) * T_;

    for (int jt = 0; jt < 8; ++jt) {
        if (jt) __syncthreads();
        const int cur = jt & 1;
        if (jt < 7) {
            int j0n = (jt + 1) * 64;
            const u16* ksrc = qkv + 512 + ((i64)b * T_ + j0n) * QKSTR + h * DK_;
            const u16* vsrc = vT_b + ((i64)(b * H_ + h) * DK_) * T_ + j0n;
#pragma unroll
            for (int t2 = 0; t2 < 2; ++t2) {
                int t = w * 2 + t2;
                gld16(ksrc + (i64)(t * 8 + (lane >> 3)) * QKSTR + lc * 8,
                      (char*)&kbuf[cur ^ 1][0] + t * 1024);
                gld16(vsrc + (i64)(t * 8 + (lane >> 3)) * T_ + lc * 8,
                      (char*)&vbuf[cur ^ 1][0] + t * 1024);
            }
        }
        const int j0 = jt * 64;

        u16 bdr[4][4];
        float acf[4];
#pragma unroll
        for (int ni = 0; ni < 4; ++ni) {
            acf[ni] = acbh[j0 + ni * 16 + lr];   // pre-scaled by SC2E
#pragma unroll
            for (int qq = 0; qq < 4; ++qq)
                bdr[ni][qq] = bdsp[(i64)qq * T_ + j0 + ni * 16 + lr];
        }

        f32x4 S[4];
        __builtin_amdgcn_s_setprio(1);
#pragma unroll
        for (int ni = 0; ni < 4; ++ni) {
            int r = ni * 16 + lr;
            bf16x8 kf0 = *reinterpret_cast<const bf16x8*>(
                &kbuf[cur][0] + r * 64 + ((g ^ (r & 7)) * 8));
            bf16x8 kf1 = *reinterpret_cast<const bf16x8*>(
                &kbuf[cur][0] + r * 64 + (((4 + g) ^ (r & 7)) * 8));
            f32x4 acc = {0.f, 0.f, 0.f, 0.f};
            acc = __builtin_amdgcn_mfma_f32_16x16x32_bf16(qw[0], kf0, acc, 0, 0, 0);
            acc = __builtin_amdgcn_mfma_f32_16x16x32_bf16(qw[1], kf1, acc, 0, 0, 0);
            S[ni] = acc;
        }
        __builtin_amdgcn_s_setprio(0);
        // S' = qk*SC2E + acf + bd (all pre-scaled; diagonal bd == 0)
#pragma unroll
        for (int ni = 0; ni < 4; ++ni) {
            int j = j0 + ni * 16 + lr;
#pragma unroll
            for (int qq = 0; qq < 4; ++qq) {
                int rel = j - (i0 + w * 16 + g * 4 + qq);
                float bdv = (rel == 1) ? 0.f : b2f(bdr[ni][qq]);
                S[ni][qq] = fmaf(S[ni][qq], SC2E, acf[ni] + bdv);
            }
        }
        // lazy defer-max: per-lane max only; cross-lane reduce only on growth
        float pl[4];
#pragma unroll
        for (int qq = 0; qq < 4; ++qq)
            pl[qq] = fmaxf(fmaxf(S[0][qq], S[1][qq]), fmaxf(S[2][qq], S[3][qq]));
        bool grow = (pl[0] > mrun[0] + 11.5f) | (pl[1] > mrun[1] + 11.5f)
                  | (pl[2] > mrun[2] + 11.5f) | (pl[3] > mrun[3] + 11.5f);
        if (__any(grow)) {
#pragma unroll
            for (int qq = 0; qq < 4; ++qq) {
                float v0 = pl[qq];
                v0 = fmaxf(v0, __shfl_xor(v0, 1));
                v0 = fmaxf(v0, __shfl_xor(v0, 2));
                v0 = fmaxf(v0, __shfl_xor(v0, 4));
                v0 = fmaxf(v0, __shfl_xor(v0, 8));
                float mnew = fmaxf(mrun[qq], v0);
                float alpha = exp2f(mrun[qq] - mnew);
                mrun[qq] = mnew;
#pragma unroll
                for (int ni = 0; ni < 4; ++ni) O[ni][qq] *= alpha;
                lrun[qq] *= alpha;       // per-lane partial rescale (uniform alpha)
            }
        }
        // exp2 + per-lane partial sums (NO cross-lane reduce here)
#pragma unroll
        for (int qq = 0; qq < 4; ++qq) {
#pragma unroll
            for (int ni = 0; ni < 4; ++ni) {
                float pv = exp2f(S[ni][qq] - mrun[qq]);
                S[ni][qq] = pv;
                lrun[qq] += pv;
            }
        }
#pragma unroll
        for (int ni = 0; ni < 4; ++ni) {
#pragma unroll
            for (int qq = 0; qq < 4; ++qq) {
                int rp = w * 16 + g * 4 + qq;
                int col = ni * 16 + lr;
                pbuf[rp * 64 + (((col >> 3) ^ (rp & 7)) * 8) + (col & 7)] =
                    f2b(S[ni][qq]);
            }
        }
        __builtin_amdgcn_s_waitcnt(0xC07F);   // lgkmcnt(0)
        __builtin_amdgcn_s_setprio(1);
#pragma unroll
        for (int kk = 0; kk < 2; ++kk) {
            int r = w * 16 + lr;
            bf16x8 aP = *reinterpret_cast<const bf16x8*>(
                &pbuf[0] + r * 64 + (((kk * 4 + g) ^ (r & 7)) * 8));
#pragma unroll
            for (int ni = 0; ni < 4; ++ni) {
                int rv = ni * 16 + lr;
                bf16x8 vf = *reinterpret_cast<const bf16x8*>(
                    &vbuf[cur][0] + rv * 64 + (((kk * 4 + g) ^ (rv & 7)) * 8));
                O[ni] = __builtin_amdgcn_mfma_f32_16x16x32_bf16(aP, vf, O[ni], 0, 0, 0);
            }
        }
        __builtin_amdgcn_s_setprio(0);
    }

    // final cross-lane l-sum reduce (once), then normalize + store
#pragma unroll
    for (int qq = 0; qq < 4; ++qq) {
        float ls = lrun[qq];
        ls += __shfl_xor(ls, 1); ls += __shfl_xor(ls, 2);
        ls += __shfl_xor(ls, 4); ls += __shfl_xor(ls, 8);
        float inv = 1.0f / ls;
        int t = i0 + w * 16 + g * 4 + qq;
        u16* orow = ctx + ((i64)b * T_ + t) * D_ + h * DK_;
#pragma unroll
        for (int ni = 0; ni < 4; ++ni)
            orow[ni * 16 + lr] = f2b(O[ni][qq] * inv);
    }
}

// ---------------------------------------------------------------- MFMA GEMM (NT): C[M,N] = A[M,K] * B[N,K]^T
// 2-phase double-buffered, BK=32, chunk-XOR LDS swizzle (both sides).
// XCD1D: 1D grid, id&127 = z (b*8+h), (id>>7)&3 = row tile, id>>9 = col tile;
//        id%8 == h pins each head's blocks to one XCD (bds write->read L2 fwd).
// QKVF: q|k -> Cb, v -> vT transposed, acb = (k.pbu)*SC2E reduce.
// BDST: rel_shift scatter of (vv+bias)*SC2E as bf16 (no loads in epilogue).
template<int BN, bool XCD1D, bool QKVF, bool OUTB, bool BIAS, bool RELU, bool ADD, bool BDST>
__global__ __launch_bounds__(256) void gemm_k(
    const u16* __restrict__ Ag, int lda, i64 sAo, i64 sAi,
    const u16* __restrict__ Bg, int ldb, i64 sBo, i64 sBi,
    void* __restrict__ Cg, int ldc, i64 sCo, i64 sCi,
    const float* __restrict__ biasg, i64 sBiaso, i64 sBiasi,
    const float* __restrict__ adds,
    u16* __restrict__ vTg, float* __restrict__ acbg,
    const float* __restrict__ pbug,
    int innerB, int K)
{
    constexpr int BM   = 128;
    constexpr int WN   = BN / 2;
    constexpr int NFN  = WN / 16;
    constexpr int NISS = (BM + BN) / 64;
    __shared__ u16 sh[2][(BM + BN) * 32];

    int bxi, byi, z;
    if constexpr (XCD1D) {
        int idd = blockIdx.x;
        z   = idd & 127;            // b*innerB + h (innerB == 8)
        bxi = (idd >> 7) & 3;
        byi = idd >> 9;
    } else {
        bxi = blockIdx.x; byi = blockIdx.y; z = blockIdx.z;
    }
    int ob = z / innerB, ib = z % innerB;
    const u16*   A16 = Ag + ob * sAo + ib * sAi;
    const u16*   Bp  = Bg + ob * sBo + ib * sBi;
    float*       Cf  = (float*)Cg + ob * sCo + ib * sCi;
    u16*         Cb  = (u16*)Cg + ob * sCo + ib * sCi;
    const float* bias = BIAS ? (biasg + ob * sBiaso + ib * sBiasi) : nullptr;
    const float* Asrc = ADD ? (adds + ob * sCo + ib * sCi) : nullptr;

    int tid = threadIdx.x;
    int w = tid >> 6, l = tid & 63;
    int row0 = bxi * BM, col0 = byi * BN;
    int wr = (w >> 1) * 64, wc = (w & 1) * WN;
    int lr = l & 15, g = l >> 4;
    int swz = (lr >> 1) & 3;

    int frb = w * 16 + (l >> 2);
    int cjk = l & 3;

    f32x4 acc[4][NFN];
#pragma unroll
    for (int mi = 0; mi < 4; ++mi)
#pragma unroll
        for (int ni = 0; ni < NFN; ++ni)
#pragma unroll
            for (int j = 0; j < 4; ++j) acc[mi][ni][j] = 0.f;

    const int nt = K / 32;

    auto STAGE = [&](int d, int kt) {
        int k0 = kt * 32;
#pragma unroll
        for (int t = 0; t < NISS; ++t) {
            int R = t * 64 + frb;
            int ccs = (cjk ^ ((R >> 1) & 3)) * 8;
            const u16* src = (R < BM) ? (A16 + (i64)(row0 + R) * lda + k0 + ccs)
                                      : (Bp  + (i64)(col0 + R - BM) * ldb + k0 + ccs);
            gld16(src, (char*)&sh[d][0] + t * 4096 + w * 1024);
        }
    };

    STAGE(0, 0);
    for (int t = 0; t < nt; ++t) {
        const int cur = t & 1;
        __syncthreads();
        if (t + 1 < nt) STAGE(cur ^ 1, t + 1);
        bf16x8 av[4], bv[NFN];
#pragma unroll
        for (int mi = 0; mi < 4; ++mi) {
            int r = wr + mi * 16 + lr;
            av[mi] = *reinterpret_cast<const bf16x8*>(
                (char*)&sh[cur][0] + r * 64 + ((g ^ swz) * 16));
        }
#pragma unroll
        for (int ni = 0; ni < NFN; ++ni) {
            int r = wc + ni * 16 + lr;
            bv[ni] = *reinterpret_cast<const bf16x8*>(
                (char*)&sh[cur][0] + BM * 64 + r * 64 + ((g ^ swz) * 16));
        }
#pragma unroll
        for (int mi = 0; mi < 4; ++mi)
#pragma unroll
            for (int ni = 0; ni < NFN; ++ni)
                acc[mi][ni] = __builtin_amdgcn_mfma_f32_16x16x32_bf16(
                    av[mi], bv[ni], acc[mi][ni], 0, 0, 0);
    }

    if constexpr (QKVF) {
        __shared__ float redbuf[2][64];
        if (col0 >= 1024) {
            int h = (col0 - 1024) >> 6;
#pragma unroll
            for (int mi = 0; mi < 4; ++mi) {
                int r0 = row0 + wr + mi * 16 + g * 4;
                int bb = r0 >> 9, t0 = r0 & 511;
#pragma unroll
                for (int ni = 0; ni < NFN; ++ni) {
                    int d = wc + ni * 16 + lr;
                    u16x4 o;
#pragma unroll
                    for (int q = 0; q < 4; ++q)
                        o[q] = f2b(acc[mi][ni][q] + bias[col0 + d]);
                    *reinterpret_cast<u16x4*>(
                        vTg + ((i64)(bb * 8 + h) * 64 + d) * T_ + t0) = o;
                }
            }
            __syncthreads();
        } else {
            const bool kreg = col0 >= 512;
            int h = (col0 - 512) >> 6;
            float psum[4][4];
#pragma unroll
            for (int mi = 0; mi < 4; ++mi)
#pragma unroll
                for (int q = 0; q < 4; ++q) psum[mi][q] = 0.f;
#pragma unroll
            for (int mi = 0; mi < 4; ++mi) {
#pragma unroll
                for (int ni = 0; ni < NFN; ++ni) {
                    int c = col0 + wc + ni * 16 + lr;
                    float pb = kreg ? pbug[h * 64 + wc + ni * 16 + lr] : 0.f;
#pragma unroll
                    for (int q = 0; q < 4; ++q) {
                        int r = row0 + wr + mi * 16 + g * 4 + q;
                        float vv = acc[mi][ni][q] + bias[c];
                        Cb[(i64)r * QKSTR + c] = f2b(vv);
                        psum[mi][q] += vv * pb;
                    }
                }
            }
            if (kreg) {
#pragma unroll
                for (int mi = 0; mi < 4; ++mi)
#pragma unroll
                    for (int q = 0; q < 4; ++q) {
                        psum[mi][q] += __shfl_xor(psum[mi][q], 1);
                        psum[mi][q] += __shfl_xor(psum[mi][q], 2);
                        psum[mi][q] += __shfl_xor(psum[mi][q], 4);
                        psum[mi][q] += __shfl_xor(psum[mi][q], 8);
                    }
                if ((w & 1) == 1 && lr == 0) {
#pragma unroll
                    for (int mi = 0; mi < 4; ++mi)
#pragma unroll
                        for (int q = 0; q < 4; ++q)
                            redbuf[w >> 1][mi * 16 + g * 4 + q] = psum[mi][q];
                }
            }
            __syncthreads();
            if (kreg && (w & 1) == 0 && lr == 0) {
#pragma unroll
                for (int mi = 0; mi < 4; ++mi)
#pragma unroll
                    for (int q = 0; q < 4; ++q) {
                        int lrow = mi * 16 + g * 4 + q;
                        int r = row0 + wr + lrow;
                        float tot = psum[mi][q] + redbuf[w >> 1][lrow];
                        acbg[(i64)(r >> 9) * 4096 + h * 512 + (r & 511)] = tot * SC2E;
                    }
            }
        }
    } else {
#pragma unroll
        for (int mi = 0; mi < 4; ++mi) {
#pragma unroll
            for (int ni = 0; ni < NFN; ++ni) {
#pragma unroll
                for (int q = 0; q < 4; ++q) {
                    int r = row0 + wr + mi * 16 + g * 4 + q;
                    int c = col0 + wc + ni * 16 + lr;
                    float vv = acc[mi][ni][q];
                    if (BIAS) vv += bias[c];
                    if (BDST) {
                        float sv = vv * SC2E;
                        if (c >= T_ - 1 - r)
                            Cb[(i64)r * T_ + (c - (T_ - 1) + r)] = f2b(sv);
                        else if (r >= 1)
                            Cb[(i64)(r - 1) * T_ + (c + r + 1)] = f2b(sv);
                    } else {
                        if (ADD)  vv += Asrc[(i64)r * ldc + c];
                        if (RELU) vv = vv > 0.f ? vv : 0.f;
                        if (OUTB) Cb[(i64)r * ldc + c] = f2b(vv);
                        else      Cf[(i64)r * ldc + c] = vv;
                    }
                }
            }
        }
    }
}

// ---------------------------------------------------------------- launch
extern "C" void kernel_launch(void* const* d_in, const int* in_sizes, int n_in,
                              void* d_out, int out_size, void* d_ws, size_t ws_size,
                              hipStream_t stream)
{
    const float* xs        = (const float*)d_in[1];
    const float* pos_emb   = (const float*)d_in[2];
    const float* ln_mha_w  = (const float*)d_in[3];
    const float* ln_mha_b  = (const float*)d_in[4];
    const float* wq        = (const float*)d_in[5];
    const float* bq        = (const float*)d_in[6];
    const float* wk        = (const float*)d_in[7];
    const float* bk        = (const float*)d_in[8];
    const float* wv        = (const float*)d_in[9];
    const float* bv        = (const float*)d_in[10];
    const float* wp        = (const float*)d_in[11];
    const float* pbu       = (const float*)d_in[12];
    const float* pbv       = (const float*)d_in[13];
    const float* wo        = (const float*)d_in[14];
    const float* bo        = (const float*)d_in[15];
    const float* ln_ff_w   = (const float*)d_in[16];
    const float* ln_ff_b   = (const float*)d_in[17];
    const float* w1        = (const float*)d_in[18];
    const float* b1        = (const float*)d_in[19];
    const float* w2        = (const float*)d_in[20];
    const float* b2        = (const float*)d_in[21];
    const float* anw       = (const float*)d_in[22];
    const float* anb       = (const float*)d_in[23];

    const i64 NTOK = (i64)B_ * T_;
    const i64 XSZ  = NTOK * D_;

    float* ws = (float*)d_ws;
    i64 off = 0;
    float* x    = ws + off;            off += XSZ;
    u16*  h_b   = (u16*)(ws + off);    off += NTOK * DF_ / 2;
    u16*  bds   = (u16*)(ws + off);    off += (i64)B_*H_*T_*T_/2;
    u16*  qk    = (u16*)(ws + off);    off += NTOK * QKSTR / 2;
    u16*  xn_b  = (u16*)(ws + off);    off += XSZ / 2;
    u16*  vT_b  = (u16*)(ws + off);    off += XSZ / 2;
    u16*  p_all = (u16*)(ws + off);    off += (i64)L_*T_*D_ / 2;
    u16*  pos_b = (u16*)(ws + off);    off += (i64)T_*D_ / 2;
    u16*  wl_b  = (u16*)(ws + off);    off += (i64)L_ * WLSTRIDE / 2;
    float* acb  = ws + off;            off += (i64)B_*H_*T_;
    float* bdb  = ws + off;            off += (i64)L_*H_*T_;
    float* bqkv = ws + off;            off += (i64)L_*1536;

    dim3 blk(256);
    dim3 gLN(2048);
    dim3 gQKV(64, 24, 1);
    dim3 gN64(64, 8, 1);
    dim3 gP(4, 4, 4);
    dim3 gBD1(2048, 1, 1);           // 1D XCD-local: id%8 == h
    dim3 gFA(1024, 1, 1);
    dim3 gFF1(64, 16, 1);

    const i64 sBT = (i64)T_ * QKSTR;

    cvt1_k<<<256, blk, 0, stream>>>(pos_emb, pos_b, 65536);
    cvt7_k<<<dim3(3328, 4), blk, 0, stream>>>(wq, wk, wv, wp, wo, w1, w2, wl_b);
    packb_k<<<24, blk, 0, stream>>>(bq, bk, bv, bqkv);

    gemm_k<128,false,false,true,false,false,false,false><<<gP, blk, 0, stream>>>(
        pos_b, D_, 0, 0, wl_b + 786432, D_, WLSTRIDE, 0,
        p_all, D_, (i64)T_*D_, 0, nullptr, 0, 0,
        nullptr, nullptr, nullptr, nullptr, 1, D_);
    for (int l = 0; l < L_; l++)
        colbias_k<<<128, blk, 0, stream>>>(
            p_all + (i64)l*T_*D_, D_, pbv + (i64)l*H_*DK_, bdb + (i64)l*H_*T_, T_);

    for (int l = 0; l < L_; l++) {
        u16* wl = wl_b + (i64)l * WLSTRIDE;
        const float* xin = (l == 0) ? xs : x;

        ln_k<true><<<gLN, blk, 0, stream>>>(xin, ln_mha_w + l*D_, ln_mha_b + l*D_, xn_b, (int)NTOK);

        gemm_k<64,false,true,false,true,false,false,false><<<gQKV, blk, 0, stream>>>(
            xn_b, D_, 0, 0, wl + 0, D_, 0, 0, qk, QKSTR, 0, 0,
            bqkv + l*1536, 0, 0, nullptr, vT_b, acb, pbu + (i64)l*H_*DK_, 1, D_);

        // bds = rel_shift(q @ p^T + bdb) * SC2E, head-local XCD placement
        gemm_k<128,true,false,false,true,false,false,true><<<gBD1, blk, 0, stream>>>(
            qk, QKSTR, sBT, DK_, p_all + (i64)l*T_*D_, D_, 0, DK_,
            bds, T_, (i64)H_ * T_ * T_, (i64)T_ * T_,
            bdb + (i64)l*H_*T_, 0, T_, nullptr, nullptr, nullptr, nullptr, H_, DK_);

        fattn_k<<<gFA, blk, 0, stream>>>(qk, vT_b, acb, bds, xn_b);

        gemm_k<64,false,false,false,true,false,true,false><<<gN64, blk, 0, stream>>>(
            xn_b, D_, 0, 0, wl + 1048576, D_, 0, 0, x, D_, 0, 0,
            bo + l*D_, 0, 0, xin, nullptr, nullptr, nullptr, 1, D_);

        ln_k<true><<<gLN, blk, 0, stream>>>(x, ln_ff_w + l*D_, ln_ff_b + l*D_, xn_b, (int)NTOK);

        gemm_k<128,false,false,true,true,true,false,false><<<gFF1, blk, 0, stream>>>(
            xn_b, D_, 0, 0, wl + 1310720, D_, 0, 0, h_b, DF_, 0, 0,
            b1 + l*DF_, 0, 0, nullptr, nullptr, nullptr, nullptr, 1, D_);
        gemm_k<64,false,false,false,true,false,true,false><<<gN64, blk, 0, stream>>>(
            h_b, DF_, 0, 0, wl + 2359296, DF_, 0, 0, x, D_, 0, 0,
            b2 + l*D_, 0, 0, x, nullptr, nullptr, nullptr, 1, DF_);
    }

    ln_k<false><<<gLN, blk, 0, stream>>>(x, anw, anb, d_out, (int)NTOK);
}

// Round 18
// 687.275 us; speedup vs baseline: 1.1214x; 1.0048x over previous
//
#include <hip/hip_runtime.h>

typedef long long i64;
typedef unsigned short u16;
typedef __attribute__((ext_vector_type(8))) short bf16x8;
typedef __attribute__((ext_vector_type(8))) unsigned short u16x8;
typedef __attribute__((ext_vector_type(4))) unsigned short u16x4;
typedef __attribute__((ext_vector_type(4))) float f32x4;

#define L_  4
#define B_  16
#define T_  512
#define D_  512
#define H_  8
#define DK_ 64
#define DF_ 2048
#define QKSTR 1024         // q|k row stride (u16); v goes straight to vT

#define WLSTRIDE 3407872   // per-layer bf16 weight count (u16)
#define SC2E 0.1803368801111f   // 0.125 * log2(e): score scale, exp2 domain

__device__ __forceinline__ u16 f2b(float f) {            // fp32 -> bf16 RNE
    unsigned u = __float_as_uint(f);
    u += 0x7FFF + ((u >> 16) & 1);
    return (u16)(u >> 16);
}
__device__ __forceinline__ float b2f(u16 b) {
    return __uint_as_float(((unsigned)b) << 16);
}
__device__ __forceinline__ void gld16(const void* g, void* l) {
    __builtin_amdgcn_global_load_lds(
        (const __attribute__((address_space(1))) void*)g,
        (__attribute__((address_space(3))) void*)l, 16, 0, 0);
}

// ---------------------------------------------------------------- fp32->bf16 converts
__global__ __launch_bounds__(256) void cvt1_k(const float* __restrict__ s,
                                              u16* __restrict__ d, int n4)
{
    int id = blockIdx.x * 256 + threadIdx.x;
    if (id >= n4) return;
    float4 u = reinterpret_cast<const float4*>(s)[id];
    u16x4 o; o[0] = f2b(u.x); o[1] = f2b(u.y); o[2] = f2b(u.z); o[3] = f2b(u.w);
    *reinterpret_cast<u16x4*>(d + (i64)id * 4) = o;
}

// all 4 layers' 7 weight tensors -> contiguous bf16 buffers (blockIdx.y = layer)
__global__ __launch_bounds__(256) void cvt7_k(
    const float* __restrict__ wq, const float* __restrict__ wk,
    const float* __restrict__ wv, const float* __restrict__ wp,
    const float* __restrict__ wo, const float* __restrict__ w1,
    const float* __restrict__ w2, u16* __restrict__ dst)
{
    int l = blockIdx.y;
    wq += (i64)l * 262144; wk += (i64)l * 262144; wv += (i64)l * 262144;
    wp += (i64)l * 262144; wo += (i64)l * 262144;
    w1 += (i64)l * 1048576; w2 += (i64)l * 1048576;
    dst += (i64)l * WLSTRIDE;
    int id = blockIdx.x * 256 + threadIdx.x;  // unit = 4 elems; total 851968
    if (id >= 851968) return;
    const float* s; i64 doff;
    if (id < 327680) {
        int seg = id >> 16, off = id & 65535;
        s = seg == 0 ? wq : seg == 1 ? wk : seg == 2 ? wv : seg == 3 ? wp : wo;
        s += (i64)off * 4;
        doff = (i64)seg * 262144 + (i64)off * 4;
    } else {
        int id2 = id - 327680;
        int seg = id2 >> 18, off = id2 & 262143;
        s = (seg ? w2 : w1) + (i64)off * 4;
        doff = 1310720 + (i64)seg * 1048576 + (i64)off * 4;
    }
    float4 u = *reinterpret_cast<const float4*>(s);
    u16x4 o; o[0] = f2b(u.x); o[1] = f2b(u.y); o[2] = f2b(u.z); o[3] = f2b(u.w);
    *reinterpret_cast<u16x4*>(dst + doff) = o;
}

// pack per-layer qkv biases into [L][1536] fp32
__global__ __launch_bounds__(256) void packb_k(const float* __restrict__ bq,
                                               const float* __restrict__ bk,
                                               const float* __restrict__ bv,
                                               float* __restrict__ dst)
{
    int id = blockIdx.x * 256 + threadIdx.x;   // L*1536 = 6144
    if (id >= L_ * 1536) return;
    int l = id / 1536, c = id % 1536;
    float v = (c < 512) ? bq[l * 512 + c]
            : (c < 1024) ? bk[l * 512 + c - 512]
                         : bv[l * 512 + c - 1024];
    dst[id] = v;
}

// ---------------------------------------------------------------- LayerNorm
template<bool OB>
__global__ __launch_bounds__(256) void ln_k(const float* __restrict__ x,
                                            const float* __restrict__ w,
                                            const float* __restrict__ b,
                                            void* __restrict__ outv, int nrows)
{
    int wid  = (blockIdx.x * 256 + threadIdx.x) >> 6;
    int lane = threadIdx.x & 63;
    if (wid >= nrows) return;
    const float* xr = x + (i64)wid * D_;
    float4 u = reinterpret_cast<const float4*>(xr)[lane * 2 + 0];
    float4 v = reinterpret_cast<const float4*>(xr)[lane * 2 + 1];
    float s = u.x + u.y + u.z + u.w + v.x + v.y + v.z + v.w;
    float q = u.x*u.x + u.y*u.y + u.z*u.z + u.w*u.w
            + v.x*v.x + v.y*v.y + v.z*v.z + v.w*v.w;
#pragma unroll
    for (int m = 1; m < 64; m <<= 1) { s += __shfl_xor(s, m); q += __shfl_xor(q, m); }
    float mu   = s * (1.0f / D_);
    float var  = q * (1.0f / D_) - mu * mu;
    float rstd = rsqrtf(var + 1e-5f);
    int c0 = lane * 8;
    float o[8];
    o[0] = (u.x - mu) * rstd * w[c0+0] + b[c0+0];
    o[1] = (u.y - mu) * rstd * w[c0+1] + b[c0+1];
    o[2] = (u.z - mu) * rstd * w[c0+2] + b[c0+2];
    o[3] = (u.w - mu) * rstd * w[c0+3] + b[c0+3];
    o[4] = (v.x - mu) * rstd * w[c0+4] + b[c0+4];
    o[5] = (v.y - mu) * rstd * w[c0+5] + b[c0+5];
    o[6] = (v.z - mu) * rstd * w[c0+6] + b[c0+6];
    o[7] = (v.w - mu) * rstd * w[c0+7] + b[c0+7];
    if (OB) {
        u16x8 ob;
#pragma unroll
        for (int i = 0; i < 8; i++) ob[i] = f2b(o[i]);
        *reinterpret_cast<u16x8*>((u16*)outv + (i64)wid * D_ + c0) = ob;
    } else {
        float4 o0 = {o[0], o[1], o[2], o[3]};
        float4 o1 = {o[4], o[5], o[6], o[7]};
        reinterpret_cast<float4*>((float*)outv + (i64)wid * D_)[lane * 2 + 0] = o0;
        reinterpret_cast<float4*>((float*)outv + (i64)wid * D_)[lane * 2 + 1] = o1;
    }
}

// ---------------------------------------------------------------- fused attention
// bds pre-shifted and pre-scaled by SC2E; acb pre-scaled at production.
// exp2-domain softmax with lazy pmax reduce + per-lane deferred l-sum.
// b decode reversed so most-recently-written bds batches are read first.
__global__ __launch_bounds__(256, 4) void fattn_k(
    const u16* __restrict__ qkv, const u16* __restrict__ vT_b,
    const float* __restrict__ acb, const u16* __restrict__ bds,
    u16* __restrict__ ctx)
{
    __shared__ u16 kbuf[2][64 * 64];
    __shared__ u16 vbuf[2][64 * 64];
    __shared__ u16 pbuf[64 * 64];

    const int id = blockIdx.x;
    const int h = id & 7, b = 15 - ((id >> 3) & 15), qt = id >> 7;
    const int i0 = qt * 64;
    const int tid = threadIdx.x;
    const int w = tid >> 6, lane = tid & 63;
    const int lr = lane & 15, g = lane >> 4;
    const int lc = (lane & 7) ^ ((lane >> 3) & 7);

    bf16x8 qw[2];
#pragma unroll
    for (int kk = 0; kk < 2; ++kk)
        qw[kk] = *reinterpret_cast<const bf16x8*>(
            qkv + ((i64)b * T_ + i0 + w * 16 + lr) * QKSTR + h * DK_ + kk * 32 + g * 8);

    {
        const u16* ksrc = qkv + 512 + ((i64)b * T_) * QKSTR + h * DK_;
        const u16* vsrc = vT_b + ((i64)(b * H_ + h) * DK_) * T_;
#pragma unroll
        for (int t2 = 0; t2 < 2; ++t2) {
            int t = w * 2 + t2;
            gld16(ksrc + (i64)(t * 8 + (lane >> 3)) * QKSTR + lc * 8,
                  (char*)&kbuf[0][0] + t * 1024);
            gld16(vsrc + (i64)(t * 8 + (lane >> 3)) * T_ + lc * 8,
                  (char*)&vbuf[0][0] + t * 1024);
        }
    }
    __syncthreads();

    float mrun[4], lrun[4];
    f32x4 O[4];
#pragma unroll
    for (int qq = 0; qq < 4; ++qq) { mrun[qq] = -1e30f; lrun[qq] = 0.f; }
#pragma unroll
    for (int ni = 0; ni < 4; ++ni) O[ni] = {0.f, 0.f, 0.f, 0.f};

    const float* acbh = acb + (i64)b * (H_ * T_) + h * T_;
    const u16* bdsp = bds + (((i64)(b * H_ + h)) << 18)
                          + (i64)(i0 + w * 16 + g * 4) * T_;

    for (int jt = 0; jt < 8; ++jt) {
        if (jt) __syncthreads();
        const int cur = jt & 1;
        if (jt < 7) {
            int j0n = (jt + 1) * 64;
            const u16* ksrc = qkv + 512 + ((i64)b * T_ + j0n) * QKSTR + h * DK_;
            const u16* vsrc = vT_b + ((i64)(b * H_ + h) * DK_) * T_ + j0n;
#pragma unroll
            for (int t2 = 0; t2 < 2; ++t2) {
                int t = w * 2 + t2;
                gld16(ksrc + (i64)(t * 8 + (lane >> 3)) * QKSTR + lc * 8,
                      (char*)&kbuf[cur ^ 1][0] + t * 1024);
                gld16(vsrc + (i64)(t * 8 + (lane >> 3)) * T_ + lc * 8,
                      (char*)&vbuf[cur ^ 1][0] + t * 1024);
            }
        }
        const int j0 = jt * 64;

        u16 bdr[4][4];
        float acf[4];
#pragma unroll
        for (int ni = 0; ni < 4; ++ni) {
            acf[ni] = acbh[j0 + ni * 16 + lr];   // pre-scaled by SC2E
#pragma unroll
            for (int qq = 0; qq < 4; ++qq)
                bdr[ni][qq] = bdsp[(i64)qq * T_ + j0 + ni * 16 + lr];
        }

        f32x4 S[4];
        __builtin_amdgcn_s_setprio(1);
#pragma unroll
        for (int ni = 0; ni < 4; ++ni) {
            int r = ni * 16 + lr;
            bf16x8 kf0 = *reinterpret_cast<const bf16x8*>(
                &kbuf[cur][0] + r * 64 + ((g ^ (r & 7)) * 8));
            bf16x8 kf1 = *reinterpret_cast<const bf16x8*>(
                &kbuf[cur][0] + r * 64 + (((4 + g) ^ (r & 7)) * 8));
            f32x4 acc = {0.f, 0.f, 0.f, 0.f};
            acc = __builtin_amdgcn_mfma_f32_16x16x32_bf16(qw[0], kf0, acc, 0, 0, 0);
            acc = __builtin_amdgcn_mfma_f32_16x16x32_bf16(qw[1], kf1, acc, 0, 0, 0);
            S[ni] = acc;
        }
        __builtin_amdgcn_s_setprio(0);
#pragma unroll
        for (int ni = 0; ni < 4; ++ni) {
            int j = j0 + ni * 16 + lr;
#pragma unroll
            for (int qq = 0; qq < 4; ++qq) {
                int rel = j - (i0 + w * 16 + g * 4 + qq);
                float bdv = (rel == 1) ? 0.f : b2f(bdr[ni][qq]);
                S[ni][qq] = fmaf(S[ni][qq], SC2E, acf[ni] + bdv);
            }
        }
        float pl[4];
#pragma unroll
        for (int qq = 0; qq < 4; ++qq)
            pl[qq] = fmaxf(fmaxf(S[0][qq], S[1][qq]), fmaxf(S[2][qq], S[3][qq]));
        bool grow = (pl[0] > mrun[0] + 11.5f) | (pl[1] > mrun[1] + 11.5f)
                  | (pl[2] > mrun[2] + 11.5f) | (pl[3] > mrun[3] + 11.5f);
        if (__any(grow)) {
#pragma unroll
            for (int qq = 0; qq < 4; ++qq) {
                float v0 = pl[qq];
                v0 = fmaxf(v0, __shfl_xor(v0, 1));
                v0 = fmaxf(v0, __shfl_xor(v0, 2));
                v0 = fmaxf(v0, __shfl_xor(v0, 4));
                v0 = fmaxf(v0, __shfl_xor(v0, 8));
                float mnew = fmaxf(mrun[qq], v0);
                float alpha = exp2f(mrun[qq] - mnew);
                mrun[qq] = mnew;
#pragma unroll
                for (int ni = 0; ni < 4; ++ni) O[ni][qq] *= alpha;
                lrun[qq] *= alpha;
            }
        }
#pragma unroll
        for (int qq = 0; qq < 4; ++qq) {
#pragma unroll
            for (int ni = 0; ni < 4; ++ni) {
                float pv = exp2f(S[ni][qq] - mrun[qq]);
                S[ni][qq] = pv;
                lrun[qq] += pv;
            }
        }
#pragma unroll
        for (int ni = 0; ni < 4; ++ni) {
#pragma unroll
            for (int qq = 0; qq < 4; ++qq) {
                int rp = w * 16 + g * 4 + qq;
                int col = ni * 16 + lr;
                pbuf[rp * 64 + (((col >> 3) ^ (rp & 7)) * 8) + (col & 7)] =
                    f2b(S[ni][qq]);
            }
        }
        __builtin_amdgcn_s_waitcnt(0xC07F);   // lgkmcnt(0)
        __builtin_amdgcn_s_setprio(1);
#pragma unroll
        for (int kk = 0; kk < 2; ++kk) {
            int r = w * 16 + lr;
            bf16x8 aP = *reinterpret_cast<const bf16x8*>(
                &pbuf[0] + r * 64 + (((kk * 4 + g) ^ (r & 7)) * 8));
#pragma unroll
            for (int ni = 0; ni < 4; ++ni) {
                int rv = ni * 16 + lr;
                bf16x8 vf = *reinterpret_cast<const bf16x8*>(
                    &vbuf[cur][0] + rv * 64 + (((kk * 4 + g) ^ (rv & 7)) * 8));
                O[ni] = __builtin_amdgcn_mfma_f32_16x16x32_bf16(aP, vf, O[ni], 0, 0, 0);
            }
        }
        __builtin_amdgcn_s_setprio(0);
    }

#pragma unroll
    for (int qq = 0; qq < 4; ++qq) {
        float ls = lrun[qq];
        ls += __shfl_xor(ls, 1); ls += __shfl_xor(ls, 2);
        ls += __shfl_xor(ls, 4); ls += __shfl_xor(ls, 8);
        float inv = 1.0f / ls;
        int t = i0 + w * 16 + g * 4 + qq;
        u16* orow = ctx + ((i64)b * T_ + t) * D_ + h * DK_;
#pragma unroll
        for (int ni = 0; ni < 4; ++ni)
            orow[ni * 16 + lr] = f2b(O[ni][qq] * inv);
    }
}

// ---------------------------------------------------------------- MFMA GEMM (NT): C[M,N] = A[M,K] * B[N,K]^T
// 2-phase double-buffered, BK=32, chunk-XOR LDS swizzle (both sides).
// XCD1D: 1D grid, id&127 = z, id%8 == h pins head's blocks to one XCD.
// QKVF: q|k -> Cb, v -> vT transposed, acb = (k.pbu)*SC2E reduce.
// PBV : all col tiles head-like: Cb write (ldc) + bdb = (p.pbv) reduce (z = layer).
// BDST: rel_shift scatter of (vv+bias)*SC2E as bf16 (no loads in epilogue).
template<int BN, bool XCD1D, bool QKVF, bool PBV, bool OUTB, bool BIAS, bool RELU, bool ADD, bool BDST>
__global__ __launch_bounds__(256) void gemm_k(
    const u16* __restrict__ Ag, int lda, i64 sAo, i64 sAi,
    const u16* __restrict__ Bg, int ldb, i64 sBo, i64 sBi,
    void* __restrict__ Cg, int ldc, i64 sCo, i64 sCi,
    const float* __restrict__ biasg, i64 sBiaso, i64 sBiasi,
    const float* __restrict__ adds,
    u16* __restrict__ vTg, float* __restrict__ acbg,
    const float* __restrict__ pbug,
    int innerB, int K)
{
    constexpr int BM   = 128;
    constexpr int WN   = BN / 2;
    constexpr int NFN  = WN / 16;
    constexpr int NISS = (BM + BN) / 64;
    __shared__ u16 sh[2][(BM + BN) * 32];

    int bxi, byi, z;
    if constexpr (XCD1D) {
        int idd = blockIdx.x;
        z   = idd & 127;
        bxi = (idd >> 7) & 3;
        byi = idd >> 9;
    } else {
        bxi = blockIdx.x; byi = blockIdx.y; z = blockIdx.z;
    }
    int ob = z / innerB, ib = z % innerB;
    const u16*   A16 = Ag + ob * sAo + ib * sAi;
    const u16*   Bp  = Bg + ob * sBo + ib * sBi;
    float*       Cf  = (float*)Cg + ob * sCo + ib * sCi;
    u16*         Cb  = (u16*)Cg + ob * sCo + ib * sCi;
    const float* bias = BIAS ? (biasg + ob * sBiaso + ib * sBiasi) : nullptr;
    const float* Asrc = ADD ? (adds + ob * sCo + ib * sCi) : nullptr;

    int tid = threadIdx.x;
    int w = tid >> 6, l = tid & 63;
    int row0 = bxi * BM, col0 = byi * BN;
    int wr = (w >> 1) * 64, wc = (w & 1) * WN;
    int lr = l & 15, g = l >> 4;
    int swz = (lr >> 1) & 3;

    int frb = w * 16 + (l >> 2);
    int cjk = l & 3;

    f32x4 acc[4][NFN];
#pragma unroll
    for (int mi = 0; mi < 4; ++mi)
#pragma unroll
        for (int ni = 0; ni < NFN; ++ni)
#pragma unroll
            for (int j = 0; j < 4; ++j) acc[mi][ni][j] = 0.f;

    const int nt = K / 32;

    auto STAGE = [&](int d, int kt) {
        int k0 = kt * 32;
#pragma unroll
        for (int t = 0; t < NISS; ++t) {
            int R = t * 64 + frb;
            int ccs = (cjk ^ ((R >> 1) & 3)) * 8;
            const u16* src = (R < BM) ? (A16 + (i64)(row0 + R) * lda + k0 + ccs)
                                      : (Bp  + (i64)(col0 + R - BM) * ldb + k0 + ccs);
            gld16(src, (char*)&sh[d][0] + t * 4096 + w * 1024);
        }
    };

    STAGE(0, 0);
    for (int t = 0; t < nt; ++t) {
        const int cur = t & 1;
        __syncthreads();
        if (t + 1 < nt) STAGE(cur ^ 1, t + 1);
        bf16x8 av[4], bv[NFN];
#pragma unroll
        for (int mi = 0; mi < 4; ++mi) {
            int r = wr + mi * 16 + lr;
            av[mi] = *reinterpret_cast<const bf16x8*>(
                (char*)&sh[cur][0] + r * 64 + ((g ^ swz) * 16));
        }
#pragma unroll
        for (int ni = 0; ni < NFN; ++ni) {
            int r = wc + ni * 16 + lr;
            bv[ni] = *reinterpret_cast<const bf16x8*>(
                (char*)&sh[cur][0] + BM * 64 + r * 64 + ((g ^ swz) * 16));
        }
#pragma unroll
        for (int mi = 0; mi < 4; ++mi)
#pragma unroll
            for (int ni = 0; ni < NFN; ++ni)
                acc[mi][ni] = __builtin_amdgcn_mfma_f32_16x16x32_bf16(
                    av[mi], bv[ni], acc[mi][ni], 0, 0, 0);
    }

    if constexpr (PBV) {
        // Cb write + bdb[h][t] = (row . pbv[h]) * SC2E reduce (rows = t, z = layer)
        __shared__ float redbufp[2][64];
        int hh = col0 >> 6;
        float psum[4][4];
#pragma unroll
        for (int mi = 0; mi < 4; ++mi)
#pragma unroll
            for (int q = 0; q < 4; ++q) psum[mi][q] = 0.f;
#pragma unroll
        for (int mi = 0; mi < 4; ++mi) {
#pragma unroll
            for (int ni = 0; ni < NFN; ++ni) {
                int c = col0 + wc + ni * 16 + lr;
                float pb = pbug[(i64)ob * 512 + hh * 64 + wc + ni * 16 + lr];
#pragma unroll
                for (int q = 0; q < 4; ++q) {
                    int r = row0 + wr + mi * 16 + g * 4 + q;
                    float vv = acc[mi][ni][q];
                    Cb[(i64)r * ldc + c] = f2b(vv);
                    psum[mi][q] += vv * pb;
                }
            }
        }
#pragma unroll
        for (int mi = 0; mi < 4; ++mi)
#pragma unroll
            for (int q = 0; q < 4; ++q) {
                psum[mi][q] += __shfl_xor(psum[mi][q], 1);
                psum[mi][q] += __shfl_xor(psum[mi][q], 2);
                psum[mi][q] += __shfl_xor(psum[mi][q], 4);
                psum[mi][q] += __shfl_xor(psum[mi][q], 8);
            }
        if ((w & 1) == 1 && lr == 0) {
#pragma unroll
            for (int mi = 0; mi < 4; ++mi)
#pragma unroll
                for (int q = 0; q < 4; ++q)
                    redbufp[w >> 1][mi * 16 + g * 4 + q] = psum[mi][q];
        }
        __syncthreads();
        if ((w & 1) == 0 && lr == 0) {
#pragma unroll
            for (int mi = 0; mi < 4; ++mi)
#pragma unroll
                for (int q = 0; q < 4; ++q) {
                    int lrow = mi * 16 + g * 4 + q;
                    int r = row0 + wr + lrow;
                    float tot = psum[mi][q] + redbufp[w >> 1][lrow];
                    acbg[(i64)ob * 4096 + hh * 512 + r] = tot * SC2E;
                }
        }
    } else if constexpr (QKVF) {
        __shared__ float redbuf[2][64];
        if (col0 >= 1024) {
            int h = (col0 - 1024) >> 6;
#pragma unroll
            for (int mi = 0; mi < 4; ++mi) {
                int r0 = row0 + wr + mi * 16 + g * 4;
                int bb = r0 >> 9, t0 = r0 & 511;
#pragma unroll
                for (int ni = 0; ni < NFN; ++ni) {
                    int d = wc + ni * 16 + lr;
                    u16x4 o;
#pragma unroll
                    for (int q = 0; q < 4; ++q)
                        o[q] = f2b(acc[mi][ni][q] + bias[col0 + d]);
                    *reinterpret_cast<u16x4*>(
                        vTg + ((i64)(bb * 8 + h) * 64 + d) * T_ + t0) = o;
                }
            }
            __syncthreads();
        } else {
            const bool kreg = col0 >= 512;
            int h = (col0 - 512) >> 6;
            float psum[4][4];
#pragma unroll
            for (int mi = 0; mi < 4; ++mi)
#pragma unroll
                for (int q = 0; q < 4; ++q) psum[mi][q] = 0.f;
#pragma unroll
            for (int mi = 0; mi < 4; ++mi) {
#pragma unroll
                for (int ni = 0; ni < NFN; ++ni) {
                    int c = col0 + wc + ni * 16 + lr;
                    float pb = kreg ? pbug[h * 64 + wc + ni * 16 + lr] : 0.f;
#pragma unroll
                    for (int q = 0; q < 4; ++q) {
                        int r = row0 + wr + mi * 16 + g * 4 + q;
                        float vv = acc[mi][ni][q] + bias[c];
                        Cb[(i64)r * QKSTR + c] = f2b(vv);
                        psum[mi][q] += vv * pb;
                    }
                }
            }
            if (kreg) {
#pragma unroll
                for (int mi = 0; mi < 4; ++mi)
#pragma unroll
                    for (int q = 0; q < 4; ++q) {
                        psum[mi][q] += __shfl_xor(psum[mi][q], 1);
                        psum[mi][q] += __shfl_xor(psum[mi][q], 2);
                        psum[mi][q] += __shfl_xor(psum[mi][q], 4);
                        psum[mi][q] += __shfl_xor(psum[mi][q], 8);
                    }
                if ((w & 1) == 1 && lr == 0) {
#pragma unroll
                    for (int mi = 0; mi < 4; ++mi)
#pragma unroll
                        for (int q = 0; q < 4; ++q)
                            redbuf[w >> 1][mi * 16 + g * 4 + q] = psum[mi][q];
                }
            }
            __syncthreads();
            if (kreg && (w & 1) == 0 && lr == 0) {
#pragma unroll
                for (int mi = 0; mi < 4; ++mi)
#pragma unroll
                    for (int q = 0; q < 4; ++q) {
                        int lrow = mi * 16 + g * 4 + q;
                        int r = row0 + wr + lrow;
                        float tot = psum[mi][q] + redbuf[w >> 1][lrow];
                        acbg[(i64)(r >> 9) * 4096 + h * 512 + (r & 511)] = tot * SC2E;
                    }
            }
        }
    } else {
#pragma unroll
        for (int mi = 0; mi < 4; ++mi) {
#pragma unroll
            for (int ni = 0; ni < NFN; ++ni) {
#pragma unroll
                for (int q = 0; q < 4; ++q) {
                    int r = row0 + wr + mi * 16 + g * 4 + q;
                    int c = col0 + wc + ni * 16 + lr;
                    float vv = acc[mi][ni][q];
                    if (BIAS) vv += bias[c];
                    if (BDST) {
                        float sv = vv * SC2E;
                        if (c >= T_ - 1 - r)
                            Cb[(i64)r * T_ + (c - (T_ - 1) + r)] = f2b(sv);
                        else if (r >= 1)
                            Cb[(i64)(r - 1) * T_ + (c + r + 1)] = f2b(sv);
                    } else {
                        if (ADD)  vv += Asrc[(i64)r * ldc + c];
                        if (RELU) vv = vv > 0.f ? vv : 0.f;
                        if (OUTB) Cb[(i64)r * ldc + c] = f2b(vv);
                        else      Cf[(i64)r * ldc + c] = vv;
                    }
                }
            }
        }
    }
}

// ---------------------------------------------------------------- launch
extern "C" void kernel_launch(void* const* d_in, const int* in_sizes, int n_in,
                              void* d_out, int out_size, void* d_ws, size_t ws_size,
                              hipStream_t stream)
{
    const float* xs        = (const float*)d_in[1];
    const float* pos_emb   = (const float*)d_in[2];
    const float* ln_mha_w  = (const float*)d_in[3];
    const float* ln_mha_b  = (const float*)d_in[4];
    const float* wq        = (const float*)d_in[5];
    const float* bq        = (const float*)d_in[6];
    const float* wk        = (const float*)d_in[7];
    const float* bk        = (const float*)d_in[8];
    const float* wv        = (const float*)d_in[9];
    const float* bv        = (const float*)d_in[10];
    const float* wp        = (const float*)d_in[11];
    const float* pbu       = (const float*)d_in[12];
    const float* pbv       = (const float*)d_in[13];
    const float* wo        = (const float*)d_in[14];
    const float* bo        = (const float*)d_in[15];
    const float* ln_ff_w   = (const float*)d_in[16];
    const float* ln_ff_b   = (const float*)d_in[17];
    const float* w1        = (const float*)d_in[18];
    const float* b1        = (const float*)d_in[19];
    const float* w2        = (const float*)d_in[20];
    const float* b2        = (const float*)d_in[21];
    const float* anw       = (const float*)d_in[22];
    const float* anb       = (const float*)d_in[23];

    const i64 NTOK = (i64)B_ * T_;
    const i64 XSZ  = NTOK * D_;

    float* ws = (float*)d_ws;
    i64 off = 0;
    float* x    = ws + off;            off += XSZ;
    u16*  h_b   = (u16*)(ws + off);    off += NTOK * DF_ / 2;
    u16*  bds   = (u16*)(ws + off);    off += (i64)B_*H_*T_*T_/2;
    u16*  qk    = (u16*)(ws + off);    off += NTOK * QKSTR / 2;
    u16*  xn_b  = (u16*)(ws + off);    off += XSZ / 2;
    u16*  vT_b  = (u16*)(ws + off);    off += XSZ / 2;
    u16*  p_all = (u16*)(ws + off);    off += (i64)L_*T_*D_ / 2;
    u16*  pos_b = (u16*)(ws + off);    off += (i64)T_*D_ / 2;
    u16*  wl_b  = (u16*)(ws + off);    off += (i64)L_ * WLSTRIDE / 2;
    float* acb  = ws + off;            off += (i64)B_*H_*T_;
    float* bdb  = ws + off;            off += (i64)L_*H_*T_;
    float* bqkv = ws + off;            off += (i64)L_*1536;

    dim3 blk(256);
    dim3 gLN(2048);
    dim3 gQKV(64, 24, 1);
    dim3 gN64(64, 8, 1);
    dim3 gPn(4, 8, 4);               // p-proj: BN=64 col tiles = heads; z = layer
    dim3 gBD1(2048, 1, 1);           // 1D XCD-local: id%8 == h
    dim3 gFA(1024, 1, 1);
    dim3 gFF1(64, 16, 1);

    const i64 sBT = (i64)T_ * QKSTR;

    cvt1_k<<<256, blk, 0, stream>>>(pos_emb, pos_b, 65536);
    cvt7_k<<<dim3(3328, 4), blk, 0, stream>>>(wq, wk, wv, wp, wo, w1, w2, wl_b);
    packb_k<<<24, blk, 0, stream>>>(bq, bk, bv, bqkv);

    // p[l] = pos_emb @ wp[l]^T (bf16) with fused bdb[l][h][t] = (p . pbv) * SC2E
    gemm_k<64,false,false,true,false,false,false,false,false><<<gPn, blk, 0, stream>>>(
        pos_b, D_, 0, 0, wl_b + 786432, D_, WLSTRIDE, 0,
        p_all, D_, (i64)T_*D_, 0, nullptr, 0, 0,
        nullptr, nullptr, bdb, pbv, 1, D_);

    for (int l = 0; l < L_; l++) {
        u16* wl = wl_b + (i64)l * WLSTRIDE;
        const float* xin = (l == 0) ? xs : x;

        ln_k<true><<<gLN, blk, 0, stream>>>(xin, ln_mha_w + l*D_, ln_mha_b + l*D_, xn_b, (int)NTOK);

        gemm_k<64,false,true,false,false,true,false,false,false><<<gQKV, blk, 0, stream>>>(
            xn_b, D_, 0, 0, wl + 0, D_, 0, 0, qk, QKSTR, 0, 0,
            bqkv + l*1536, 0, 0, nullptr, vT_b, acb, pbu + (i64)l*H_*DK_, 1, D_);

        // bds = rel_shift(q @ p^T + bdb) * SC2E, head-local XCD placement
        gemm_k<128,true,false,false,false,true,false,false,true><<<gBD1, blk, 0, stream>>>(
            qk, QKSTR, sBT, DK_, p_all + (i64)l*T_*D_, D_, 0, DK_,
            bds, T_, (i64)H_ * T_ * T_, (i64)T_ * T_,
            bdb + (i64)l*H_*T_, 0, T_, nullptr, nullptr, nullptr, nullptr, H_, DK_);

        fattn_k<<<gFA, blk, 0, stream>>>(qk, vT_b, acb, bds, xn_b);

        gemm_k<64,false,false,false,false,true,false,true,false><<<gN64, blk, 0, stream>>>(
            xn_b, D_, 0, 0, wl + 1048576, D_, 0, 0, x, D_, 0, 0,
            bo + l*D_, 0, 0, xin, nullptr, nullptr, nullptr, 1, D_);

        ln_k<true><<<gLN, blk, 0, stream>>>(x, ln_ff_w + l*D_, ln_ff_b + l*D_, xn_b, (int)NTOK);

        gemm_k<128,false,false,false,true,true,true,false,false><<<gFF1, blk, 0, stream>>>(
            xn_b, D_, 0, 0, wl + 1310720, D_, 0, 0, h_b, DF_, 0, 0,
            b1 + l*DF_, 0, 0, nullptr, nullptr, nullptr, nullptr, 1, D_);
        gemm_k<64,false,false,false,false,true,false,true,false><<<gN64, blk, 0, stream>>>(
            h_b, DF_, 0, 0, wl + 2359296, DF_, 0, 0, x, D_, 0, 0,
            b2 + l*D_, 0, 0, x, nullptr, nullptr, nullptr, 1, DF_);
    }

    ln_k<false><<<gLN, blk, 0, stream>>>(x, anw, anb, d_out, (int)NTOK);
}